// Round 4
// baseline (134.192 us; speedup 1.0000x reference)
//
#include <hip/hip_runtime.h>

// ---------------- constants ----------------
#define HEADS 8
#define DH 40
constexpr int Bn   = 8;
constexpr int Cc   = 320;
constexpr int Nn   = 4096;        // tokens per batch (64*64)
constexpr int CTX  = 77;
constexpr float LN_EPS = 1e-5f;
constexpr float SCALE  = 0.15811388300841897f; // 40^-0.5

typedef short bf16x8 __attribute__((ext_vector_type(8)));
typedef float f32x4  __attribute__((ext_vector_type(4)));
typedef unsigned short us;

__device__ inline us f2bf(float f) {
    unsigned u = __float_as_uint(f);
    u += 0x7fffu + ((u >> 16) & 1u);
    return (us)(u >> 16);
}

// ---------------- all weight transposes fp32[K][O] -> bf16[O][K], one launch ----------------
__global__ __launch_bounds__(256) void wtrans_all(const float* __restrict__ Wq,
                                                  const float* __restrict__ Wk,
                                                  const float* __restrict__ Wv,
                                                  const float* __restrict__ Wout,
                                                  us* __restrict__ WqT,
                                                  us* __restrict__ WkT,
                                                  us* __restrict__ WvT,
                                                  us* __restrict__ WoutT) {
    int id = blockIdx.x;
    const float* in; us* out; int K, t;
    if (id < 100)      { in = Wq;   out = WqT;   K = 320; t = id; }
    else if (id < 340) { in = Wk;   out = WkT;   K = 768; t = id - 100; }
    else if (id < 580) { in = Wv;   out = WvT;   K = 768; t = id - 340; }
    else               { in = Wout; out = WoutT; K = 320; t = id - 580; }
    int ktiles = K >> 5;
    int kb = (t % ktiles) * 32, ob = (t / ktiles) * 32;

    __shared__ float tile[32][33];
    int tx = threadIdx.x & 31, ty = threadIdx.x >> 5; // ty 0..7
    #pragma unroll
    for (int i = 0; i < 32; i += 8)
        tile[ty + i][tx] = in[(size_t)(kb + ty + i) * 320 + ob + tx];
    __syncthreads();
    #pragma unroll
    for (int i = 0; i < 32; i += 8)
        out[(size_t)(ob + ty + i) * K + kb + tx] = f2bf(tile[tx][ty + i]);
}

// ---------------- fused LayerNorm + Q projection ----------------
__global__ __launch_bounds__(256) void ln_q_fused(const float* __restrict__ x,
                                                  const float* __restrict__ gamma,
                                                  const float* __restrict__ beta,
                                                  const us* __restrict__ WqT,
                                                  us* __restrict__ q) {
    __shared__ __align__(16) us xnt[64 * 328];
    __shared__ float red1[4][64], red2[4][64];
    __shared__ float mu_s[64], rs_s[64];

    int b  = blockIdx.x >> 6;
    int t0 = (blockIdx.x & 63) * 64;
    int tid = threadIdx.x;
    int tl = tid & 63, cg = tid >> 6;
    const float* xb = x + (size_t)b * Cc * Nn + t0 + tl;

    float s1 = 0.f, s2 = 0.f;
    #pragma unroll 8
    for (int i = 0; i < 80; ++i) {
        float v = xb[(size_t)(cg * 80 + i) * Nn];
        s1 += v; s2 += v * v;
    }
    red1[cg][tl] = s1; red2[cg][tl] = s2;
    __syncthreads();
    if (tid < 64) {
        float a1 = red1[0][tl] + red1[1][tl] + red1[2][tl] + red1[3][tl];
        float a2 = red2[0][tl] + red2[1][tl] + red2[2][tl] + red2[3][tl];
        float mu = a1 * (1.0f / Cc);
        float var = a2 * (1.0f / Cc) - mu * mu;
        mu_s[tl] = mu; rs_s[tl] = rsqrtf(var + LN_EPS);
    }
    __syncthreads();
    float mu = mu_s[tl], rs = rs_s[tl];
    #pragma unroll 4
    for (int i = 0; i < 40; ++i) {
        int c = cg * 80 + i * 2;
        float v0 = xb[(size_t)c * Nn];
        float v1 = xb[(size_t)(c + 1) * Nn];
        unsigned lo = f2bf((v0 - mu) * rs * gamma[c] + beta[c]);
        unsigned hi = f2bf((v1 - mu) * rs * gamma[c + 1] + beta[c + 1]);
        *(unsigned*)&xnt[tl * 328 + c] = lo | (hi << 16);
    }
    __syncthreads();

    int lane = tid & 63, w = tid >> 6;
    int lr = lane & 15, g = lane >> 4;
    f32x4 acc[4][5] = {};   // [token-tile][out-tile]
    const us* Bbase = WqT + (size_t)(w * 80 + lr) * 320 + g * 8;
    for (int kc = 0; kc < 320; kc += 32) {
        bf16x8 bfr[5];
        #pragma unroll
        for (int nt = 0; nt < 5; ++nt)
            bfr[nt] = *(const bf16x8*)(Bbase + nt * 16 * 320 + kc);
        bf16x8 afr[4];
        #pragma unroll
        for (int mt = 0; mt < 4; ++mt)
            afr[mt] = *(const bf16x8*)&xnt[(mt * 16 + lr) * 328 + kc + g * 8];
        #pragma unroll
        for (int mt = 0; mt < 4; ++mt)
            #pragma unroll
            for (int nt = 0; nt < 5; ++nt)
                acc[mt][nt] = __builtin_amdgcn_mfma_f32_16x16x32_bf16(afr[mt], bfr[nt], acc[mt][nt], 0, 0, 0);
    }
    us* qb = q + ((size_t)b * Nn + t0) * 320;
    #pragma unroll
    for (int mt = 0; mt < 4; ++mt)
        #pragma unroll
        for (int nt = 0; nt < 5; ++nt)
            #pragma unroll
            for (int r = 0; r < 4; ++r)
                qb[(size_t)(mt * 16 + g * 4 + r) * 320 + w * 80 + nt * 16 + lr] = f2bf(acc[mt][nt][r]);
}

// ---------------- K/V projection: ctx fp32 [616][768] x W^T -> bf16 [616][320] ----------------
__global__ __launch_bounds__(256) void gemm_kv(const float* __restrict__ ctx,
                                               const us* __restrict__ WkT,
                                               const us* __restrict__ WvT,
                                               us* __restrict__ kbuf,
                                               us* __restrict__ vbuf) {
    const us* Bt = blockIdx.z ? WvT : WkT;
    us* Cm = blockIdx.z ? vbuf : kbuf;
    constexpr int K = 768, M = 616;
    __shared__ __align__(16) char Al[64 * 128];
    __shared__ __align__(16) char Bl[64 * 128];
    int m0 = blockIdx.x * 64;
    int n0 = blockIdx.y * 64;
    int tid = threadIdx.x;
    int lane = tid & 63, wave = tid >> 6;
    int wm = (wave >> 1) * 32, wn = (wave & 1) * 32;

    f32x4 acc[2][2] = {};

    for (int kc = 0; kc < K; kc += 64) {
        #pragma unroll
        for (int i = 0; i < 2; ++i) {
            int chunk = tid + 256 * i;
            int r = chunk >> 3, c8 = chunk & 7;
            int off = (r * 128 + c8 * 16) ^ ((r & 7) << 4);
            int gr = m0 + r;
            uint4 av = make_uint4(0, 0, 0, 0);
            if (gr < M) {
                float4 f0 = *(const float4*)(ctx + (size_t)gr * K + kc + c8 * 8);
                float4 f1 = *(const float4*)(ctx + (size_t)gr * K + kc + c8 * 8 + 4);
                av.x = f2bf(f0.x) | ((unsigned)f2bf(f0.y) << 16);
                av.y = f2bf(f0.z) | ((unsigned)f2bf(f0.w) << 16);
                av.z = f2bf(f1.x) | ((unsigned)f2bf(f1.y) << 16);
                av.w = f2bf(f1.z) | ((unsigned)f2bf(f1.w) << 16);
            }
            *(uint4*)(Al + off) = av;
            *(uint4*)(Bl + off) = *(const uint4*)(Bt + (size_t)(n0 + r) * K + kc + c8 * 8);
        }
        __syncthreads();

        #pragma unroll
        for (int kk = 0; kk < 64; kk += 32) {
            bf16x8 a[2], bfr[2];
            int lr = lane & 15;
            int lkb = (kk + (lane >> 4) * 8) * 2;
            #pragma unroll
            for (int mi = 0; mi < 2; ++mi) {
                int row = wm + mi * 16 + lr;
                a[mi] = *(const bf16x8*)(Al + ((row * 128 + lkb) ^ ((row & 7) << 4)));
            }
            #pragma unroll
            for (int ni = 0; ni < 2; ++ni) {
                int row = wn + ni * 16 + lr;
                bfr[ni] = *(const bf16x8*)(Bl + ((row * 128 + lkb) ^ ((row & 7) << 4)));
            }
            #pragma unroll
            for (int mi = 0; mi < 2; ++mi)
                #pragma unroll
                for (int ni = 0; ni < 2; ++ni)
                    acc[mi][ni] = __builtin_amdgcn_mfma_f32_16x16x32_bf16(a[mi], bfr[ni], acc[mi][ni], 0, 0, 0);
        }
        __syncthreads();
    }

    int lr = lane & 15, lq = lane >> 4;
    #pragma unroll
    for (int mi = 0; mi < 2; ++mi)
        #pragma unroll
        for (int ni = 0; ni < 2; ++ni)
            #pragma unroll
            for (int r = 0; r < 4; ++r) {
                int row = m0 + wm + mi * 16 + lq * 4 + r;
                int col = n0 + wn + ni * 16 + lr;
                if (row < M)
                    Cm[(size_t)row * 320 + col] = f2bf(acc[mi][ni][r]);
            }
}

// ---------------- VW precompute: vwT[b][c][h*80+j] = sum_d Wout[h*40+d][c] * V[b,j,h*40+d] ----------------
__global__ __launch_bounds__(256) void gemm_vw(const us* __restrict__ WoutT,
                                               const us* __restrict__ vbuf,
                                               us* __restrict__ vwT) {
    int b = blockIdx.z, h = blockIdx.y, cb = blockIdx.x * 64;
    int tid = threadIdx.x, lane = tid & 63, w = tid >> 6;
    int lr = lane & 15, g = lane >> 4;

    int crow = cb + w * 16 + lr;
    const us* ab = WoutT + (size_t)crow * 320 + h * DH;
    bf16x8 a0 = *(const bf16x8*)(ab + g * 8);
    bf16x8 a1 = {};
    if (g == 0) a1 = *(const bf16x8*)(ab + 32);

    f32x4 acc[5] = {};
    #pragma unroll
    for (int nt = 0; nt < 5; ++nt) {
        int j = nt * 16 + lr;
        bool jv = j < CTX;
        const us* kr = vbuf + (size_t)(b * CTX + (jv ? j : 0)) * 320 + h * DH;
        bf16x8 b0 = {}, b1 = {};
        if (jv) b0 = *(const bf16x8*)(kr + g * 8);
        if (jv && g == 0) b1 = *(const bf16x8*)(kr + 32);
        acc[nt] = __builtin_amdgcn_mfma_f32_16x16x32_bf16(a0, b0, acc[nt], 0, 0, 0);
        acc[nt] = __builtin_amdgcn_mfma_f32_16x16x32_bf16(a1, b1, acc[nt], 0, 0, 0);
    }

    #pragma unroll
    for (int nt = 0; nt < 5; ++nt)
        #pragma unroll
        for (int r = 0; r < 4; ++r) {
            int c = cb + w * 16 + g * 4 + r;
            float val = (nt == 4 && lr >= 13) ? 0.f : acc[nt][r];
            vwT[((size_t)(b * 320 + c)) * 640 + h * 80 + nt * 16 + lr] = f2bf(val);
        }
}

// ---------------- fused attention + out-proj ----------------
// block = 32 tokens of one batch. QK^T (K frags from L2-hot kbuf) -> per-head
// softmax -> P [32][640] bf16 LDS (XOR-swizzled, key-pads zero) ->
// out^T tile = VW^T @ P^T  (K=640) -> coalesced [b,c,n] store + bias + residual.
__global__ __launch_bounds__(256) void attn_out(const us* __restrict__ q,
                                                const us* __restrict__ kbuf,
                                                const us* __restrict__ vwT,
                                                const float* __restrict__ bout,
                                                const float* __restrict__ x,
                                                float* __restrict__ out) {
    __shared__ __align__(16) char xq[32 * 640];    // q tile, swizzled
    __shared__ __align__(16) char Pl[32 * 1280];   // P bf16 [32][640], swizzled

    int b = blockIdx.y;
    int t0 = blockIdx.x * 32;
    int tid = threadIdx.x, lane = tid & 63, w = tid >> 6;
    int lr = lane & 15, g = lane >> 4;

    // ---- stage q tile (coalesced) ----
    const us* qb = q + ((size_t)b * Nn + t0) * 320;
    #pragma unroll
    for (int i = 0; i < 5; ++i) {
        int id = tid + 256 * i;
        int row = id / 40, seg = id - row * 40;
        *(uint4*)(xq + ((row * 640 + seg * 16) ^ ((row & 7) << 4))) =
            *(const uint4*)(qb + row * 320 + seg * 8);
    }
    __syncthreads();

    // ---- QK^T + softmax for heads 2w, 2w+1 ----
    #pragma unroll
    for (int hh = 0; hh < 2; ++hh) {
        int h = w * 2 + hh;
        bf16x8 a[2][2];
        #pragma unroll
        for (int mt = 0; mt < 2; ++mt) {
            int row = mt * 16 + lr;
            a[mt][0] = *(const bf16x8*)(xq + ((row * 640 + h * 80 + g * 16) ^ ((row & 7) << 4)));
            bf16x8 z = {};
            a[mt][1] = z;
            if (g == 0)
                a[mt][1] = *(const bf16x8*)(xq + ((row * 640 + h * 80 + 64) ^ ((row & 7) << 4)));
        }

        f32x4 S[2][5] = {};
        #pragma unroll
        for (int nt = 0; nt < 5; ++nt) {
            int j = nt * 16 + lr;
            bool jv = j < CTX;
            const us* kr = kbuf + (size_t)(b * CTX + (jv ? j : 0)) * 320 + h * DH;
            bf16x8 b0 = {}, b1 = {};
            if (jv) b0 = *(const bf16x8*)(kr + g * 8);
            if (jv && g == 0) b1 = *(const bf16x8*)(kr + 32);
            #pragma unroll
            for (int mt = 0; mt < 2; ++mt) {
                S[mt][nt] = __builtin_amdgcn_mfma_f32_16x16x32_bf16(a[mt][0], b0, S[mt][nt], 0, 0, 0);
                S[mt][nt] = __builtin_amdgcn_mfma_f32_16x16x32_bf16(a[mt][1], b1, S[mt][nt], 0, 0, 0);
            }
        }

        // per-head softmax (no max: scores bounded), normalized P to LDS
        #pragma unroll
        for (int mt = 0; mt < 2; ++mt) {
            float pv[5][4];
            #pragma unroll
            for (int nt = 0; nt < 5; ++nt)
                #pragma unroll
                for (int r = 0; r < 4; ++r)
                    pv[nt][r] = (nt == 4 && lr >= 13) ? 0.f : __expf(S[mt][nt][r] * SCALE);
            #pragma unroll
            for (int r = 0; r < 4; ++r) {
                float su = pv[0][r] + pv[1][r] + pv[2][r] + pv[3][r] + pv[4][r];
                #pragma unroll
                for (int off = 1; off < 16; off <<= 1)
                    su += __shfl_xor(su, off);
                float inv = 1.0f / su;
                int row = mt * 16 + g * 4 + r;
                #pragma unroll
                for (int nt = 0; nt < 5; ++nt)
                    *(us*)(Pl + ((row * 1280 + (h * 80 + nt * 16 + lr) * 2) ^ ((row & 7) << 4))) =
                        f2bf(pv[nt][r] * inv);
            }
        }
    }
    __syncthreads();

    // ---- out^T = VW^T @ P^T : wave w -> co slice [80w, 80w+80) ----
    f32x4 o[5][2] = {};
    const us* vw = vwT + (size_t)b * 320 * 640;
    int cw = w * 80;
    for (int ks = 0; ks < 20; ++ks) {
        bf16x8 pb[2];
        #pragma unroll
        for (int nt = 0; nt < 2; ++nt) {
            int row = nt * 16 + lr;
            pb[nt] = *(const bf16x8*)(Pl + ((row * 1280 + ks * 64 + g * 16) ^ ((row & 7) << 4)));
        }
        #pragma unroll
        for (int mi = 0; mi < 5; ++mi) {
            bf16x8 av = *(const bf16x8*)(vw + (size_t)(cw + mi * 16 + lr) * 640 + ks * 32 + g * 8);
            #pragma unroll
            for (int nt = 0; nt < 2; ++nt)
                o[mi][nt] = __builtin_amdgcn_mfma_f32_16x16x32_bf16(av, pb[nt], o[mi][nt], 0, 0, 0);
        }
    }

    // ---- epilogue: coalesced store + bias + residual ----
    #pragma unroll
    for (int mi = 0; mi < 5; ++mi)
        #pragma unroll
        for (int r = 0; r < 4; ++r) {
            int co = cw + mi * 16 + g * 4 + r;
            float bo = bout[co];
            #pragma unroll
            for (int nt = 0; nt < 2; ++nt) {
                size_t oi = ((size_t)(b * 320 + co)) * 4096 + t0 + nt * 16 + lr;
                out[oi] = o[mi][nt][r] + bo + x[oi];
            }
        }
}

// ---------------- launch ----------------
extern "C" void kernel_launch(void* const* d_in, const int* in_sizes, int n_in,
                              void* d_out, int out_size, void* d_ws, size_t ws_size,
                              hipStream_t stream) {
    const float* x     = (const float*)d_in[0];
    const float* ctx   = (const float*)d_in[1];
    const float* Wq    = (const float*)d_in[2];
    const float* Wk    = (const float*)d_in[3];
    const float* Wv    = (const float*)d_in[4];
    const float* Wout  = (const float*)d_in[5];
    const float* bout  = (const float*)d_in[6];
    const float* gamma = (const float*)d_in[7];
    const float* beta  = (const float*)d_in[8];
    float* out = (float*)d_out;
    char* ws = (char*)d_ws;

    // workspace layout (bytes)
    us* q     = (us*)(ws);                         // 32768*320*2 = 20971520
    us* kbuf  = (us*)(ws + 20971520);              // 616*320*2   = 394240
    us* vbuf  = (us*)(ws + 21365760);              // 394240
    us* vwT   = (us*)(ws + 21760000);              // 8*320*640*2 = 3276800
    us* WqT   = (us*)(ws + 25036800);              // 204800
    us* WkT   = (us*)(ws + 25241600);              // 491520
    us* WvT   = (us*)(ws + 25733120);              // 491520
    us* WoutT = (us*)(ws + 26224640);              // 204800

    wtrans_all<<<dim3(680), 256, 0, stream>>>(Wq, Wk, Wv, Wout, WqT, WkT, WvT, WoutT);
    ln_q_fused<<<dim3(512), 256, 0, stream>>>(x, gamma, beta, WqT, q);
    gemm_kv<<<dim3(10, 5, 2), 256, 0, stream>>>(ctx, WkT, WvT, kbuf, vbuf);
    gemm_vw<<<dim3(5, 8, 8), 256, 0, stream>>>(WoutT, vbuf, vwT);
    attn_out<<<dim3(128, 8), 256, 0, stream>>>(q, kbuf, vwT, bout, x, out);
}

// Round 5
// 120.493 us; speedup vs baseline: 1.1137x; 1.1137x over previous
//
#include <hip/hip_runtime.h>

// ---------------- constants ----------------
#define HEADS 8
#define DH 40
constexpr int Bn   = 8;
constexpr int Cc   = 320;
constexpr int Nn   = 4096;        // tokens per batch (64*64)
constexpr int CTX  = 77;
constexpr float LN_EPS = 1e-5f;
constexpr float SCALE  = 0.15811388300841897f; // 40^-0.5

typedef short bf16x8 __attribute__((ext_vector_type(8)));
typedef float f32x4  __attribute__((ext_vector_type(4)));
typedef unsigned short us;

__device__ inline us f2bf(float f) {
    unsigned u = __float_as_uint(f);
    u += 0x7fffu + ((u >> 16) & 1u);
    return (us)(u >> 16);
}

// ---------------- all weight transposes fp32[K][O] -> bf16[O][K], one launch ----------------
__global__ __launch_bounds__(256) void wtrans_all(const float* __restrict__ Wq,
                                                  const float* __restrict__ Wk,
                                                  const float* __restrict__ Wv,
                                                  const float* __restrict__ Wout,
                                                  us* __restrict__ WqT,
                                                  us* __restrict__ WkT,
                                                  us* __restrict__ WvT,
                                                  us* __restrict__ WoutT) {
    int id = blockIdx.x;
    const float* in; us* out; int K, t;
    if (id < 100)      { in = Wq;   out = WqT;   K = 320; t = id; }
    else if (id < 340) { in = Wk;   out = WkT;   K = 768; t = id - 100; }
    else if (id < 580) { in = Wv;   out = WvT;   K = 768; t = id - 340; }
    else               { in = Wout; out = WoutT; K = 320; t = id - 580; }
    int ktiles = K >> 5;
    int kb = (t % ktiles) * 32, ob = (t / ktiles) * 32;

    __shared__ float tile[32][33];
    int tx = threadIdx.x & 31, ty = threadIdx.x >> 5; // ty 0..7
    #pragma unroll
    for (int i = 0; i < 32; i += 8)
        tile[ty + i][tx] = in[(size_t)(kb + ty + i) * 320 + ob + tx];
    __syncthreads();
    #pragma unroll
    for (int i = 0; i < 32; i += 8)
        out[(size_t)(ob + ty + i) * K + kb + tx] = f2bf(tile[tx][ty + i]);
}

// ---------------- fused LayerNorm + Q projection ----------------
__global__ __launch_bounds__(256) void ln_q_fused(const float* __restrict__ x,
                                                  const float* __restrict__ gamma,
                                                  const float* __restrict__ beta,
                                                  const us* __restrict__ WqT,
                                                  us* __restrict__ q) {
    __shared__ __align__(16) us xnt[64 * 328];
    __shared__ float red1[4][64], red2[4][64];
    __shared__ float mu_s[64], rs_s[64];

    int b  = blockIdx.x >> 6;
    int t0 = (blockIdx.x & 63) * 64;
    int tid = threadIdx.x;
    int tl = tid & 63, cg = tid >> 6;
    const float* xb = x + (size_t)b * Cc * Nn + t0 + tl;

    float s1 = 0.f, s2 = 0.f;
    #pragma unroll 8
    for (int i = 0; i < 80; ++i) {
        float v = xb[(size_t)(cg * 80 + i) * Nn];
        s1 += v; s2 += v * v;
    }
    red1[cg][tl] = s1; red2[cg][tl] = s2;
    __syncthreads();
    if (tid < 64) {
        float a1 = red1[0][tl] + red1[1][tl] + red1[2][tl] + red1[3][tl];
        float a2 = red2[0][tl] + red2[1][tl] + red2[2][tl] + red2[3][tl];
        float mu = a1 * (1.0f / Cc);
        float var = a2 * (1.0f / Cc) - mu * mu;
        mu_s[tl] = mu; rs_s[tl] = rsqrtf(var + LN_EPS);
    }
    __syncthreads();
    float mu = mu_s[tl], rs = rs_s[tl];
    #pragma unroll 4
    for (int i = 0; i < 40; ++i) {
        int c = cg * 80 + i * 2;
        float v0 = xb[(size_t)c * Nn];
        float v1 = xb[(size_t)(c + 1) * Nn];
        unsigned lo = f2bf((v0 - mu) * rs * gamma[c] + beta[c]);
        unsigned hi = f2bf((v1 - mu) * rs * gamma[c + 1] + beta[c + 1]);
        *(unsigned*)&xnt[tl * 328 + c] = lo | (hi << 16);
    }
    __syncthreads();

    int lane = tid & 63, w = tid >> 6;
    int lr = lane & 15, g = lane >> 4;
    f32x4 acc[4][5] = {};   // [token-tile][out-tile]
    const us* Bbase = WqT + (size_t)(w * 80 + lr) * 320 + g * 8;
    for (int kc = 0; kc < 320; kc += 32) {
        bf16x8 bfr[5];
        #pragma unroll
        for (int nt = 0; nt < 5; ++nt)
            bfr[nt] = *(const bf16x8*)(Bbase + nt * 16 * 320 + kc);
        bf16x8 afr[4];
        #pragma unroll
        for (int mt = 0; mt < 4; ++mt)
            afr[mt] = *(const bf16x8*)&xnt[(mt * 16 + lr) * 328 + kc + g * 8];
        #pragma unroll
        for (int mt = 0; mt < 4; ++mt)
            #pragma unroll
            for (int nt = 0; nt < 5; ++nt)
                acc[mt][nt] = __builtin_amdgcn_mfma_f32_16x16x32_bf16(afr[mt], bfr[nt], acc[mt][nt], 0, 0, 0);
    }
    us* qb = q + ((size_t)b * Nn + t0) * 320;
    #pragma unroll
    for (int mt = 0; mt < 4; ++mt)
        #pragma unroll
        for (int nt = 0; nt < 5; ++nt)
            #pragma unroll
            for (int r = 0; r < 4; ++r)
                qb[(size_t)(mt * 16 + g * 4 + r) * 320 + w * 80 + nt * 16 + lr] = f2bf(acc[mt][nt][r]);
}

// ---------------- K/V projection: ctx fp32 [616][768] x W^T -> bf16 [616][320] ----------------
__global__ __launch_bounds__(256) void gemm_kv(const float* __restrict__ ctx,
                                               const us* __restrict__ WkT,
                                               const us* __restrict__ WvT,
                                               us* __restrict__ kbuf,
                                               us* __restrict__ vbuf) {
    const us* Bt = blockIdx.z ? WvT : WkT;
    us* Cm = blockIdx.z ? vbuf : kbuf;
    constexpr int K = 768, M = 616;
    __shared__ __align__(16) char Al[64 * 128];
    __shared__ __align__(16) char Bl[64 * 128];
    int m0 = blockIdx.x * 64;
    int n0 = blockIdx.y * 64;
    int tid = threadIdx.x;
    int lane = tid & 63, wave = tid >> 6;
    int wm = (wave >> 1) * 32, wn = (wave & 1) * 32;

    f32x4 acc[2][2] = {};

    for (int kc = 0; kc < K; kc += 64) {
        #pragma unroll
        for (int i = 0; i < 2; ++i) {
            int chunk = tid + 256 * i;
            int r = chunk >> 3, c8 = chunk & 7;
            int off = (r * 128 + c8 * 16) ^ ((r & 7) << 4);
            int gr = m0 + r;
            uint4 av = make_uint4(0, 0, 0, 0);
            if (gr < M) {
                float4 f0 = *(const float4*)(ctx + (size_t)gr * K + kc + c8 * 8);
                float4 f1 = *(const float4*)(ctx + (size_t)gr * K + kc + c8 * 8 + 4);
                av.x = f2bf(f0.x) | ((unsigned)f2bf(f0.y) << 16);
                av.y = f2bf(f0.z) | ((unsigned)f2bf(f0.w) << 16);
                av.z = f2bf(f1.x) | ((unsigned)f2bf(f1.y) << 16);
                av.w = f2bf(f1.z) | ((unsigned)f2bf(f1.w) << 16);
            }
            *(uint4*)(Al + off) = av;
            *(uint4*)(Bl + off) = *(const uint4*)(Bt + (size_t)(n0 + r) * K + kc + c8 * 8);
        }
        __syncthreads();

        #pragma unroll
        for (int kk = 0; kk < 64; kk += 32) {
            bf16x8 a[2], bfr[2];
            int lr = lane & 15;
            int lkb = (kk + (lane >> 4) * 8) * 2;
            #pragma unroll
            for (int mi = 0; mi < 2; ++mi) {
                int row = wm + mi * 16 + lr;
                a[mi] = *(const bf16x8*)(Al + ((row * 128 + lkb) ^ ((row & 7) << 4)));
            }
            #pragma unroll
            for (int ni = 0; ni < 2; ++ni) {
                int row = wn + ni * 16 + lr;
                bfr[ni] = *(const bf16x8*)(Bl + ((row * 128 + lkb) ^ ((row & 7) << 4)));
            }
            #pragma unroll
            for (int mi = 0; mi < 2; ++mi)
                #pragma unroll
                for (int ni = 0; ni < 2; ++ni)
                    acc[mi][ni] = __builtin_amdgcn_mfma_f32_16x16x32_bf16(a[mi], bfr[ni], acc[mi][ni], 0, 0, 0);
        }
        __syncthreads();
    }

    int lr = lane & 15, lq = lane >> 4;
    #pragma unroll
    for (int mi = 0; mi < 2; ++mi)
        #pragma unroll
        for (int ni = 0; ni < 2; ++ni)
            #pragma unroll
            for (int r = 0; r < 4; ++r) {
                int row = m0 + wm + mi * 16 + lq * 4 + r;
                int col = n0 + wn + ni * 16 + lr;
                if (row < M)
                    Cm[(size_t)row * 320 + col] = f2bf(acc[mi][ni][r]);
            }
}

// ---------------- VW precompute: vwT[b][c][h*80+j] = sum_d Wout[h*40+d][c] * V[b,j,h*40+d] ----------------
__global__ __launch_bounds__(256) void gemm_vw(const us* __restrict__ WoutT,
                                               const us* __restrict__ vbuf,
                                               us* __restrict__ vwT) {
    int b = blockIdx.z, h = blockIdx.y, cb = blockIdx.x * 64;
    int tid = threadIdx.x, lane = tid & 63, w = tid >> 6;
    int lr = lane & 15, g = lane >> 4;

    int crow = cb + w * 16 + lr;
    const us* ab = WoutT + (size_t)crow * 320 + h * DH;
    bf16x8 a0 = *(const bf16x8*)(ab + g * 8);
    bf16x8 a1 = {};
    if (g == 0) a1 = *(const bf16x8*)(ab + 32);

    f32x4 acc[5] = {};
    #pragma unroll
    for (int nt = 0; nt < 5; ++nt) {
        int j = nt * 16 + lr;
        bool jv = j < CTX;
        const us* kr = vbuf + (size_t)(b * CTX + (jv ? j : 0)) * 320 + h * DH;
        bf16x8 b0 = {}, b1 = {};
        if (jv) b0 = *(const bf16x8*)(kr + g * 8);
        if (jv && g == 0) b1 = *(const bf16x8*)(kr + 32);
        acc[nt] = __builtin_amdgcn_mfma_f32_16x16x32_bf16(a0, b0, acc[nt], 0, 0, 0);
        acc[nt] = __builtin_amdgcn_mfma_f32_16x16x32_bf16(a1, b1, acc[nt], 0, 0, 0);
    }

    #pragma unroll
    for (int nt = 0; nt < 5; ++nt)
        #pragma unroll
        for (int r = 0; r < 4; ++r) {
            int c = cb + w * 16 + g * 4 + r;
            float val = (nt == 4 && lr >= 13) ? 0.f : acc[nt][r];
            vwT[((size_t)(b * 320 + c)) * 640 + h * 80 + nt * 16 + lr] = f2bf(val);
        }
}

// ---------------- repack K into MFMA-fragment order ----------------
// kF[((b*8+h)*5+nt)*2+kc][lane] : lane(=g*16+lr) holds K[b][j=nt*16+lr][h*40+kc*32+g*8 .. +8]
__global__ __launch_bounds__(256) void repack_kf(const us* __restrict__ kbuf,
                                                 us* __restrict__ kF) {
    int wid = blockIdx.x * 4 + (threadIdx.x >> 6);   // 0..639
    int lane = threadIdx.x & 63, lr = lane & 15, g = lane >> 4;
    int kc = wid & 1, nt = (wid >> 1) % 5, h = (wid / 10) & 7, b = wid / 80;
    int j = nt * 16 + lr, d0 = kc * 32 + g * 8;
    bf16x8 v = {};
    if (j < CTX && d0 < DH)
        v = *(const bf16x8*)(kbuf + ((size_t)(b * CTX + j)) * 320 + h * DH + d0);
    ((bf16x8*)kF)[(size_t)wid * 64 + lane] = v;
}

// ---------------- repack VW into MFMA-fragment order ----------------
// vwF[((b*4+w)*20+ks)*5+mi][lane] : lane holds VW[b][co=w*80+mi*16+lr][ks*32+g*8 .. +8]
__global__ __launch_bounds__(256) void repack_vwf(const us* __restrict__ vwT,
                                                  us* __restrict__ vwF) {
    int wid = blockIdx.x * 4 + (threadIdx.x >> 6);   // 0..3199
    int lane = threadIdx.x & 63, lr = lane & 15, g = lane >> 4;
    int mi = wid % 5, ks = (wid / 5) % 20, w = (wid / 100) & 3, b = wid / 400;
    int co = w * 80 + mi * 16 + lr, k = ks * 32 + g * 8;
    bf16x8 v = *(const bf16x8*)(vwT + ((size_t)(b * 320 + co)) * 640 + k);
    ((bf16x8*)vwF)[(size_t)wid * 64 + lane] = v;
}

// ---------------- fused attention + out-proj (fragment-coalesced operands) ----------------
__global__ __launch_bounds__(256) void attn_out(const us* __restrict__ q,
                                                const us* __restrict__ kF,
                                                const us* __restrict__ vwF,
                                                const float* __restrict__ bout,
                                                const float* __restrict__ x,
                                                float* __restrict__ out) {
    __shared__ __align__(16) char xq[32 * 640];    // q tile, swizzled
    __shared__ __align__(16) char Pl[32 * 1280];   // P bf16 [32][640], swizzled

    int b = blockIdx.y;
    int t0 = blockIdx.x * 32;
    int tid = threadIdx.x, lane = tid & 63, w = tid >> 6;
    int lr = lane & 15, g = lane >> 4;

    // ---- stage q tile (coalesced) ----
    const us* qb = q + ((size_t)b * Nn + t0) * 320;
    #pragma unroll
    for (int i = 0; i < 5; ++i) {
        int id = tid + 256 * i;
        int row = id / 40, seg = id - row * 40;
        *(uint4*)(xq + ((row * 640 + seg * 16) ^ ((row & 7) << 4))) =
            *(const uint4*)(qb + row * 320 + seg * 8);
    }
    __syncthreads();

    // ---- QK^T + softmax for heads 2w, 2w+1 ----
    const bf16x8* kfb = (const bf16x8*)kF;
    #pragma unroll
    for (int hh = 0; hh < 2; ++hh) {
        int h = w * 2 + hh;
        bf16x8 a[2][2];
        #pragma unroll
        for (int mt = 0; mt < 2; ++mt) {
            int row = mt * 16 + lr;
            a[mt][0] = *(const bf16x8*)(xq + ((row * 640 + h * 80 + g * 16) ^ ((row & 7) << 4)));
            bf16x8 z = {};
            a[mt][1] = z;
            if (g == 0)
                a[mt][1] = *(const bf16x8*)(xq + ((row * 640 + h * 80 + 64) ^ ((row & 7) << 4)));
        }

        f32x4 S[2][5] = {};
        size_t kfh = (size_t)((b * 8 + h) * 10) * 64;
        #pragma unroll
        for (int nt = 0; nt < 5; ++nt) {
            bf16x8 b0 = kfb[kfh + (nt * 2 + 0) * 64 + lane];
            bf16x8 b1 = kfb[kfh + (nt * 2 + 1) * 64 + lane];
            #pragma unroll
            for (int mt = 0; mt < 2; ++mt) {
                S[mt][nt] = __builtin_amdgcn_mfma_f32_16x16x32_bf16(a[mt][0], b0, S[mt][nt], 0, 0, 0);
                S[mt][nt] = __builtin_amdgcn_mfma_f32_16x16x32_bf16(a[mt][1], b1, S[mt][nt], 0, 0, 0);
            }
        }

        // per-head softmax (no max: scores bounded), normalized P to LDS
        #pragma unroll
        for (int mt = 0; mt < 2; ++mt) {
            float pv[5][4];
            #pragma unroll
            for (int nt = 0; nt < 5; ++nt)
                #pragma unroll
                for (int r = 0; r < 4; ++r)
                    pv[nt][r] = (nt == 4 && lr >= 13) ? 0.f : __expf(S[mt][nt][r] * SCALE);
            #pragma unroll
            for (int r = 0; r < 4; ++r) {
                float su = pv[0][r] + pv[1][r] + pv[2][r] + pv[3][r] + pv[4][r];
                #pragma unroll
                for (int off = 1; off < 16; off <<= 1)
                    su += __shfl_xor(su, off);
                float inv = 1.0f / su;
                int row = mt * 16 + g * 4 + r;
                #pragma unroll
                for (int nt = 0; nt < 5; ++nt)
                    *(us*)(Pl + ((row * 1280 + (h * 80 + nt * 16 + lr) * 2) ^ ((row & 7) << 4))) =
                        f2bf(pv[nt][r] * inv);
            }
        }
    }
    __syncthreads();

    // ---- out^T = VW^T @ P^T : wave w -> co slice [80w, 80w+80), frag-coalesced VW ----
    f32x4 o[5][2] = {};
    const bf16x8* vwb = (const bf16x8*)vwF + (size_t)((b * 4 + w) * 100) * 64;
    for (int ks = 0; ks < 20; ++ks) {
        bf16x8 pb[2];
        #pragma unroll
        for (int nt = 0; nt < 2; ++nt) {
            int row = nt * 16 + lr;
            pb[nt] = *(const bf16x8*)(Pl + ((row * 1280 + ks * 64 + g * 16) ^ ((row & 7) << 4)));
        }
        #pragma unroll
        for (int mi = 0; mi < 5; ++mi) {
            bf16x8 av = vwb[(ks * 5 + mi) * 64 + lane];
            #pragma unroll
            for (int nt = 0; nt < 2; ++nt)
                o[mi][nt] = __builtin_amdgcn_mfma_f32_16x16x32_bf16(av, pb[nt], o[mi][nt], 0, 0, 0);
        }
    }

    // ---- epilogue: coalesced store + bias + residual ----
    int cw = w * 80;
    #pragma unroll
    for (int mi = 0; mi < 5; ++mi)
        #pragma unroll
        for (int r = 0; r < 4; ++r) {
            int co = cw + mi * 16 + g * 4 + r;
            float bo = bout[co];
            #pragma unroll
            for (int nt = 0; nt < 2; ++nt) {
                size_t oi = ((size_t)(b * 320 + co)) * 4096 + t0 + nt * 16 + lr;
                out[oi] = o[mi][nt][r] + bo + x[oi];
            }
        }
}

// ---------------- launch ----------------
extern "C" void kernel_launch(void* const* d_in, const int* in_sizes, int n_in,
                              void* d_out, int out_size, void* d_ws, size_t ws_size,
                              hipStream_t stream) {
    const float* x     = (const float*)d_in[0];
    const float* ctx   = (const float*)d_in[1];
    const float* Wq    = (const float*)d_in[2];
    const float* Wk    = (const float*)d_in[3];
    const float* Wv    = (const float*)d_in[4];
    const float* Wout  = (const float*)d_in[5];
    const float* bout  = (const float*)d_in[6];
    const float* gamma = (const float*)d_in[7];
    const float* beta  = (const float*)d_in[8];
    float* out = (float*)d_out;
    char* ws = (char*)d_ws;

    // workspace layout (bytes)
    us* q     = (us*)(ws);                         // 32768*320*2 = 20971520
    us* kbuf  = (us*)(ws + 20971520);              // 394240
    us* vbuf  = (us*)(ws + 21365760);              // 394240
    us* vwT   = (us*)(ws + 21760000);              // 3276800
    us* vwF   = (us*)(ws + 25036800);              // 3276800
    us* kF    = (us*)(ws + 28313600);              // 640*64*16 = 655360
    us* WqT   = (us*)(ws + 28968960);              // 204800
    us* WkT   = (us*)(ws + 29173760);              // 491520
    us* WvT   = (us*)(ws + 29665280);              // 491520
    us* WoutT = (us*)(ws + 30156800);              // 204800

    wtrans_all<<<dim3(680), 256, 0, stream>>>(Wq, Wk, Wv, Wout, WqT, WkT, WvT, WoutT);
    ln_q_fused<<<dim3(512), 256, 0, stream>>>(x, gamma, beta, WqT, q);
    gemm_kv<<<dim3(10, 5, 2), 256, 0, stream>>>(ctx, WkT, WvT, kbuf, vbuf);
    gemm_vw<<<dim3(5, 8, 8), 256, 0, stream>>>(WoutT, vbuf, vwT);
    repack_kf<<<dim3(160), 256, 0, stream>>>(kbuf, kF);
    repack_vwf<<<dim3(800), 256, 0, stream>>>(vwT, vwF);
    attn_out<<<dim3(128, 8), 256, 0, stream>>>(q, kF, vwF, bout, x, out);
}

// Round 6
// 97.992 us; speedup vs baseline: 1.3694x; 1.2296x over previous
//
#include <hip/hip_runtime.h>

// ---------------- constants ----------------
#define HEADS 8
#define DH 40
constexpr int Bn   = 8;
constexpr int Cc   = 320;
constexpr int Nn   = 4096;        // tokens per batch (64*64)
constexpr int CTX  = 77;
constexpr float LN_EPS = 1e-5f;
constexpr float SCALE  = 0.15811388300841897f; // 40^-0.5

typedef short bf16x8 __attribute__((ext_vector_type(8)));
typedef float f32x4  __attribute__((ext_vector_type(4)));
typedef unsigned short us;

__device__ inline us f2bf(float f) {
    unsigned u = __float_as_uint(f);
    u += 0x7fffu + ((u >> 16) & 1u);
    return (us)(u >> 16);
}

// ---------------- weight transposes (Wk, Wv, Wout) fp32[K][O] -> bf16[O][K] ----------------
__global__ __launch_bounds__(256) void wtrans_all(const float* __restrict__ Wk,
                                                  const float* __restrict__ Wv,
                                                  const float* __restrict__ Wout,
                                                  us* __restrict__ WkT,
                                                  us* __restrict__ WvT,
                                                  us* __restrict__ WoutT) {
    int id = blockIdx.x;
    const float* in; us* out; int K, t;
    if (id < 240)      { in = Wk;   out = WkT;   K = 768; t = id; }
    else if (id < 480) { in = Wv;   out = WvT;   K = 768; t = id - 240; }
    else               { in = Wout; out = WoutT; K = 320; t = id - 480; }
    int ktiles = K >> 5;
    int kb = (t % ktiles) * 32, ob = (t / ktiles) * 32;

    __shared__ float tile[32][33];
    int tx = threadIdx.x & 31, ty = threadIdx.x >> 5; // ty 0..7
    #pragma unroll
    for (int i = 0; i < 32; i += 8)
        tile[ty + i][tx] = in[(size_t)(kb + ty + i) * 320 + ob + tx];
    __syncthreads();
    #pragma unroll
    for (int i = 0; i < 32; i += 8)
        out[(size_t)(ob + ty + i) * K + kb + tx] = f2bf(tile[tx][ty + i]);
}

// ---------------- Wq -> MFMA B-fragment order ----------------
// wqF[(ct*10+kc)][lane=(g*16+lr)] : 8 bf16 = Wq[kc*32+g*8+e][ct*16+lr]
__global__ __launch_bounds__(256) void wq_frag(const float* __restrict__ Wq,
                                               us* __restrict__ wqF) {
    int wid = blockIdx.x * 4 + (threadIdx.x >> 6);  // 0..199
    int lane = threadIdx.x & 63, lr = lane & 15, g = lane >> 4;
    int ct = wid / 10, kc = wid % 10;
    int k0 = kc * 32 + g * 8, co = ct * 16 + lr;
    us tmp[8];
    #pragma unroll
    for (int e = 0; e < 8; ++e)
        tmp[e] = f2bf(Wq[(size_t)(k0 + e) * 320 + co]);
    ((uint4*)wqF)[(size_t)wid * 64 + lane] = *(uint4*)tmp;
}

// ---------------- fused LayerNorm + Q projection -> qF (fragment order) ----------------
// qF frag id = (gt*8 + h)*2 + kc, gt = global token-16-tile; lane (g,lr) holds
// q[gt*16+lr][h*40 + kc*32 + g*8 .. +8] (zero where d' >= 40).
__global__ __launch_bounds__(256, 3) void ln_q_fused(const float* __restrict__ x,
                                                     const float* __restrict__ gamma,
                                                     const float* __restrict__ beta,
                                                     const us* __restrict__ wqF,
                                                     us* __restrict__ qF) {
    __shared__ __align__(16) us xnt[64 * 328];
    __shared__ float red1[4][64], red2[4][64];
    __shared__ float mu_s[64], rs_s[64];

    int b  = blockIdx.x >> 6;
    int t0 = (blockIdx.x & 63) * 64;
    int tid = threadIdx.x;
    int tl = tid & 63, cg = tid >> 6;
    const float* xb = x + (size_t)b * Cc * Nn + t0 + tl;

    float xr[80];
    float s1 = 0.f, s2 = 0.f;
    #pragma unroll
    for (int i = 0; i < 80; ++i) {
        float v = xb[(size_t)(cg * 80 + i) * Nn];
        xr[i] = v;
        s1 += v; s2 += v * v;
    }
    red1[cg][tl] = s1; red2[cg][tl] = s2;
    __syncthreads();
    if (tid < 64) {
        float a1 = red1[0][tl] + red1[1][tl] + red1[2][tl] + red1[3][tl];
        float a2 = red2[0][tl] + red2[1][tl] + red2[2][tl] + red2[3][tl];
        float mu = a1 * (1.0f / Cc);
        float var = a2 * (1.0f / Cc) - mu * mu;
        mu_s[tl] = mu; rs_s[tl] = rsqrtf(var + LN_EPS);
    }
    __syncthreads();
    float mu = mu_s[tl], rs = rs_s[tl];
    #pragma unroll
    for (int i = 0; i < 40; ++i) {
        int c = cg * 80 + i * 2;
        unsigned lo = f2bf((xr[i * 2]     - mu) * rs * gamma[c]     + beta[c]);
        unsigned hi = f2bf((xr[i * 2 + 1] - mu) * rs * gamma[c + 1] + beta[c + 1]);
        *(unsigned*)&xnt[tl * 328 + c] = lo | (hi << 16);
    }
    __syncthreads();

    int lane = tid & 63, w = tid >> 6;
    int lr = lane & 15, g = lane >> 4;
    f32x4 acc[4][5] = {};   // [token-tile][out-tile]
    const bf16x8* wq = (const bf16x8*)wqF;
    for (int kc = 0; kc < 10; ++kc) {
        bf16x8 bfr[5];
        #pragma unroll
        for (int nt = 0; nt < 5; ++nt)
            bfr[nt] = wq[(size_t)((w * 5 + nt) * 10 + kc) * 64 + lane];
        bf16x8 afr[4];
        #pragma unroll
        for (int mt = 0; mt < 4; ++mt)
            afr[mt] = *(const bf16x8*)&xnt[(mt * 16 + lr) * 328 + kc * 32 + g * 8];
        #pragma unroll
        for (int mt = 0; mt < 4; ++mt)
            #pragma unroll
            for (int nt = 0; nt < 5; ++nt)
                acc[mt][nt] = __builtin_amdgcn_mfma_f32_16x16x32_bf16(afr[mt], bfr[nt], acc[mt][nt], 0, 0, 0);
    }
    __syncthreads();   // xnt fully consumed; reuse as q-tile [64 tok][co 320]

    #pragma unroll
    for (int mt = 0; mt < 4; ++mt)
        #pragma unroll
        for (int nt = 0; nt < 5; ++nt)
            #pragma unroll
            for (int r = 0; r < 4; ++r)
                xnt[(mt * 16 + g * 4 + r) * 328 + w * 80 + nt * 16 + lr] = f2bf(acc[mt][nt][r]);
    __syncthreads();

    // emit 64 fragment blobs (4 tiles x 8 heads x 2 kc), coalesced 16B/lane
    int fw = tid >> 6;
    size_t gtb = (size_t)b * 256 + (blockIdx.x & 63) * 4;
    #pragma unroll
    for (int it = 0; it < 16; ++it) {
        int f = it * 4 + fw;
        int tile = f >> 4, h = (f >> 1) & 7, kc = f & 1;
        int dp = kc * 32 + g * 8;
        uint4 v = make_uint4(0, 0, 0, 0);
        if (dp < DH)
            v = *(uint4*)&xnt[(tile * 16 + lr) * 328 + h * DH + dp];
        ((uint4*)qF)[((gtb + tile) * 16 + h * 2 + kc) * 64 + lane] = v;
    }
}

// ---------------- K/V projection: ctx fp32 [616][768] x W^T -> bf16 [616][320] ----------------
__global__ __launch_bounds__(256) void gemm_kv(const float* __restrict__ ctx,
                                               const us* __restrict__ WkT,
                                               const us* __restrict__ WvT,
                                               us* __restrict__ kbuf,
                                               us* __restrict__ vbuf) {
    const us* Bt = blockIdx.z ? WvT : WkT;
    us* Cm = blockIdx.z ? vbuf : kbuf;
    constexpr int K = 768, M = 616;
    __shared__ __align__(16) char Al[64 * 128];
    __shared__ __align__(16) char Bl[64 * 128];
    int m0 = blockIdx.x * 64;
    int n0 = blockIdx.y * 64;
    int tid = threadIdx.x;
    int lane = tid & 63, wave = tid >> 6;
    int wm = (wave >> 1) * 32, wn = (wave & 1) * 32;

    f32x4 acc[2][2] = {};

    for (int kc = 0; kc < K; kc += 64) {
        #pragma unroll
        for (int i = 0; i < 2; ++i) {
            int chunk = tid + 256 * i;
            int r = chunk >> 3, c8 = chunk & 7;
            int off = (r * 128 + c8 * 16) ^ ((r & 7) << 4);
            int gr = m0 + r;
            uint4 av = make_uint4(0, 0, 0, 0);
            if (gr < M) {
                float4 f0 = *(const float4*)(ctx + (size_t)gr * K + kc + c8 * 8);
                float4 f1 = *(const float4*)(ctx + (size_t)gr * K + kc + c8 * 8 + 4);
                av.x = f2bf(f0.x) | ((unsigned)f2bf(f0.y) << 16);
                av.y = f2bf(f0.z) | ((unsigned)f2bf(f0.w) << 16);
                av.z = f2bf(f1.x) | ((unsigned)f2bf(f1.y) << 16);
                av.w = f2bf(f1.z) | ((unsigned)f2bf(f1.w) << 16);
            }
            *(uint4*)(Al + off) = av;
            *(uint4*)(Bl + off) = *(const uint4*)(Bt + (size_t)(n0 + r) * K + kc + c8 * 8);
        }
        __syncthreads();

        #pragma unroll
        for (int kk = 0; kk < 64; kk += 32) {
            bf16x8 a[2], bfr[2];
            int lr = lane & 15;
            int lkb = (kk + (lane >> 4) * 8) * 2;
            #pragma unroll
            for (int mi = 0; mi < 2; ++mi) {
                int row = wm + mi * 16 + lr;
                a[mi] = *(const bf16x8*)(Al + ((row * 128 + lkb) ^ ((row & 7) << 4)));
            }
            #pragma unroll
            for (int ni = 0; ni < 2; ++ni) {
                int row = wn + ni * 16 + lr;
                bfr[ni] = *(const bf16x8*)(Bl + ((row * 128 + lkb) ^ ((row & 7) << 4)));
            }
            #pragma unroll
            for (int mi = 0; mi < 2; ++mi)
                #pragma unroll
                for (int ni = 0; ni < 2; ++ni)
                    acc[mi][ni] = __builtin_amdgcn_mfma_f32_16x16x32_bf16(a[mi], bfr[ni], acc[mi][ni], 0, 0, 0);
        }
        __syncthreads();
    }

    int lr = lane & 15, lq = lane >> 4;
    #pragma unroll
    for (int mi = 0; mi < 2; ++mi)
        #pragma unroll
        for (int ni = 0; ni < 2; ++ni)
            #pragma unroll
            for (int r = 0; r < 4; ++r) {
                int row = m0 + wm + mi * 16 + lq * 4 + r;
                int col = n0 + wn + ni * 16 + lr;
                if (row < M)
                    Cm[(size_t)row * 320 + col] = f2bf(acc[mi][ni][r]);
            }
}

// ---------------- VW precompute: vwT[b][c][h*80+j] = sum_d Wout[h*40+d][c] * V[b,j,h*40+d] ----------------
__global__ __launch_bounds__(256) void gemm_vw(const us* __restrict__ WoutT,
                                               const us* __restrict__ vbuf,
                                               us* __restrict__ vwT) {
    int b = blockIdx.z, h = blockIdx.y, cb = blockIdx.x * 64;
    int tid = threadIdx.x, lane = tid & 63, w = tid >> 6;
    int lr = lane & 15, g = lane >> 4;

    int crow = cb + w * 16 + lr;
    const us* ab = WoutT + (size_t)crow * 320 + h * DH;
    bf16x8 a0 = *(const bf16x8*)(ab + g * 8);
    bf16x8 a1 = {};
    if (g == 0) a1 = *(const bf16x8*)(ab + 32);

    f32x4 acc[5] = {};
    #pragma unroll
    for (int nt = 0; nt < 5; ++nt) {
        int j = nt * 16 + lr;
        bool jv = j < CTX;
        const us* kr = vbuf + (size_t)(b * CTX + (jv ? j : 0)) * 320 + h * DH;
        bf16x8 b0 = {}, b1 = {};
        if (jv) b0 = *(const bf16x8*)(kr + g * 8);
        if (jv && g == 0) b1 = *(const bf16x8*)(kr + 32);
        acc[nt] = __builtin_amdgcn_mfma_f32_16x16x32_bf16(a0, b0, acc[nt], 0, 0, 0);
        acc[nt] = __builtin_amdgcn_mfma_f32_16x16x32_bf16(a1, b1, acc[nt], 0, 0, 0);
    }

    #pragma unroll
    for (int nt = 0; nt < 5; ++nt)
        #pragma unroll
        for (int r = 0; r < 4; ++r) {
            int c = cb + w * 16 + g * 4 + r;
            float val = (nt == 4 && lr >= 13) ? 0.f : acc[nt][r];
            vwT[((size_t)(b * 320 + c)) * 640 + h * 80 + nt * 16 + lr] = f2bf(val);
        }
}

// ---------------- repack K into MFMA-fragment order ----------------
__global__ __launch_bounds__(256) void repack_kf(const us* __restrict__ kbuf,
                                                 us* __restrict__ kF) {
    int wid = blockIdx.x * 4 + (threadIdx.x >> 6);   // 0..639
    int lane = threadIdx.x & 63, lr = lane & 15, g = lane >> 4;
    int kc = wid & 1, nt = (wid >> 1) % 5, h = (wid / 10) & 7, b = wid / 80;
    int j = nt * 16 + lr, d0 = kc * 32 + g * 8;
    bf16x8 v = {};
    if (j < CTX && d0 < DH)
        v = *(const bf16x8*)(kbuf + ((size_t)(b * CTX + j)) * 320 + h * DH + d0);
    ((bf16x8*)kF)[(size_t)wid * 64 + lane] = v;
}

// ---------------- repack VW into MFMA-fragment order ----------------
__global__ __launch_bounds__(256) void repack_vwf(const us* __restrict__ vwT,
                                                  us* __restrict__ vwF) {
    int wid = blockIdx.x * 4 + (threadIdx.x >> 6);   // 0..3199
    int lane = threadIdx.x & 63, lr = lane & 15, g = lane >> 4;
    int mi = wid % 5, ks = (wid / 5) % 20, w = (wid / 100) & 3, b = wid / 400;
    int co = w * 80 + mi * 16 + lr, k = ks * 32 + g * 8;
    bf16x8 v = *(const bf16x8*)(vwT + ((size_t)(b * 320 + co)) * 640 + k);
    ((bf16x8*)vwF)[(size_t)wid * 64 + lane] = v;
}

// ---------------- fused attention + out-proj ----------------
// 1024 blocks; b = bid&7 (XCD-local vwF/kF), 32 tokens each. LDS = Pl only (40 KB).
__global__ __launch_bounds__(256, 3) void attn_out(const us* __restrict__ qF,
                                                   const us* __restrict__ kF,
                                                   const us* __restrict__ vwF,
                                                   const float* __restrict__ bout,
                                                   const float* __restrict__ x,
                                                   float* __restrict__ out) {
    __shared__ __align__(16) char Pl[32 * 1280];   // P bf16 [32][640], swizzled

    int bid = blockIdx.x;
    int b = bid & 7, ts = bid >> 3;
    int t0 = ts * 32;
    int tid = threadIdx.x, lane = tid & 63, w = tid >> 6;
    int lr = lane & 15, g = lane >> 4;

    const bf16x8* qfb = (const bf16x8*)qF;
    const bf16x8* kfb = (const bf16x8*)kF;

    // ---- QK^T + softmax for heads 2w, 2w+1 ----
    #pragma unroll
    for (int hh = 0; hh < 2; ++hh) {
        int h = w * 2 + hh;
        bf16x8 a[2][2];
        #pragma unroll
        for (int mt = 0; mt < 2; ++mt) {
            size_t fb = (((size_t)b * 256 + ts * 2 + mt) * 8 + h) * 2;
            a[mt][0] = qfb[(fb + 0) * 64 + lane];
            a[mt][1] = qfb[(fb + 1) * 64 + lane];
        }

        f32x4 S[2][5] = {};
        size_t kfh = (size_t)((b * 8 + h) * 10) * 64;
        #pragma unroll
        for (int nt = 0; nt < 5; ++nt) {
            bf16x8 b0 = kfb[kfh + (nt * 2 + 0) * 64 + lane];
            bf16x8 b1 = kfb[kfh + (nt * 2 + 1) * 64 + lane];
            #pragma unroll
            for (int mt = 0; mt < 2; ++mt) {
                S[mt][nt] = __builtin_amdgcn_mfma_f32_16x16x32_bf16(a[mt][0], b0, S[mt][nt], 0, 0, 0);
                S[mt][nt] = __builtin_amdgcn_mfma_f32_16x16x32_bf16(a[mt][1], b1, S[mt][nt], 0, 0, 0);
            }
        }

        // per-head softmax (no max: scores bounded), normalized P to LDS
        #pragma unroll
        for (int mt = 0; mt < 2; ++mt) {
            float pv[5][4];
            #pragma unroll
            for (int nt = 0; nt < 5; ++nt)
                #pragma unroll
                for (int r = 0; r < 4; ++r)
                    pv[nt][r] = (nt == 4 && lr >= 13) ? 0.f : __expf(S[mt][nt][r] * SCALE);
            #pragma unroll
            for (int r = 0; r < 4; ++r) {
                float su = pv[0][r] + pv[1][r] + pv[2][r] + pv[3][r] + pv[4][r];
                #pragma unroll
                for (int off = 1; off < 16; off <<= 1)
                    su += __shfl_xor(su, off);
                float inv = 1.0f / su;
                int row = mt * 16 + g * 4 + r;
                #pragma unroll
                for (int nt = 0; nt < 5; ++nt)
                    *(us*)(Pl + ((row * 1280 + (h * 80 + nt * 16 + lr) * 2) ^ ((row & 7) << 4))) =
                        f2bf(pv[nt][r] * inv);
            }
        }
    }
    __syncthreads();

    // ---- out^T = VW^T @ P^T : wave w -> co slice [80w, 80w+80) ----
    // register double-buffered vwF frags (hide L2 latency)
    f32x4 o[5][2] = {};
    const bf16x8* vwb = (const bf16x8*)vwF + (size_t)((b * 4 + w) * 100) * 64 + lane;
    bf16x8 av0[5], av1[5];
    #pragma unroll
    for (int mi = 0; mi < 5; ++mi)
        av0[mi] = vwb[mi * 64];

    #pragma unroll
    for (int ks = 0; ks < 20; ks += 2) {
        #pragma unroll
        for (int mi = 0; mi < 5; ++mi)
            av1[mi] = vwb[((ks + 1) * 5 + mi) * 64];
        {
            bf16x8 pb[2];
            #pragma unroll
            for (int nt = 0; nt < 2; ++nt) {
                int row = nt * 16 + lr;
                pb[nt] = *(const bf16x8*)(Pl + ((row * 1280 + ks * 64 + g * 16) ^ ((row & 7) << 4)));
            }
            #pragma unroll
            for (int mi = 0; mi < 5; ++mi)
                #pragma unroll
                for (int nt = 0; nt < 2; ++nt)
                    o[mi][nt] = __builtin_amdgcn_mfma_f32_16x16x32_bf16(av0[mi], pb[nt], o[mi][nt], 0, 0, 0);
        }
        if (ks + 2 < 20) {
            #pragma unroll
            for (int mi = 0; mi < 5; ++mi)
                av0[mi] = vwb[((ks + 2) * 5 + mi) * 64];
        }
        {
            bf16x8 pb[2];
            #pragma unroll
            for (int nt = 0; nt < 2; ++nt) {
                int row = nt * 16 + lr;
                pb[nt] = *(const bf16x8*)(Pl + ((row * 1280 + (ks + 1) * 64 + g * 16) ^ ((row & 7) << 4)));
            }
            #pragma unroll
            for (int mi = 0; mi < 5; ++mi)
                #pragma unroll
                for (int nt = 0; nt < 2; ++nt)
                    o[mi][nt] = __builtin_amdgcn_mfma_f32_16x16x32_bf16(av1[mi], pb[nt], o[mi][nt], 0, 0, 0);
        }
    }

    // ---- epilogue: coalesced store + bias + residual ----
    int cw = w * 80;
    #pragma unroll
    for (int mi = 0; mi < 5; ++mi)
        #pragma unroll
        for (int r = 0; r < 4; ++r) {
            int co = cw + mi * 16 + g * 4 + r;
            float bo = bout[co];
            #pragma unroll
            for (int nt = 0; nt < 2; ++nt) {
                size_t oi = ((size_t)(b * 320 + co)) * 4096 + t0 + nt * 16 + lr;
                out[oi] = o[mi][nt][r] + bo + x[oi];
            }
        }
}

// ---------------- launch ----------------
extern "C" void kernel_launch(void* const* d_in, const int* in_sizes, int n_in,
                              void* d_out, int out_size, void* d_ws, size_t ws_size,
                              hipStream_t stream) {
    const float* x     = (const float*)d_in[0];
    const float* ctx   = (const float*)d_in[1];
    const float* Wq    = (const float*)d_in[2];
    const float* Wk    = (const float*)d_in[3];
    const float* Wv    = (const float*)d_in[4];
    const float* Wout  = (const float*)d_in[5];
    const float* bout  = (const float*)d_in[6];
    const float* gamma = (const float*)d_in[7];
    const float* beta  = (const float*)d_in[8];
    float* out = (float*)d_out;
    char* ws = (char*)d_ws;

    // workspace layout (bytes)
    us* qF    = (us*)(ws);                 // 2048 tiles * 16 frags * 1 KB = 33554432
    us* kbuf  = (us*)(ws + 33554432);      // 394240
    us* vbuf  = (us*)(ws + 33948672);      // 394240
    us* vwT   = (us*)(ws + 34342912);      // 3276800
    us* vwF   = (us*)(ws + 37619712);      // 3276800
    us* kF    = (us*)(ws + 40896512);      // 655360
    us* wqF   = (us*)(ws + 41551872);      // 204800
    us* WkT   = (us*)(ws + 41756672);      // 491520
    us* WvT   = (us*)(ws + 42248192);      // 491520
    us* WoutT = (us*)(ws + 42739712);      // 204800

    wtrans_all<<<dim3(580), 256, 0, stream>>>(Wk, Wv, Wout, WkT, WvT, WoutT);
    wq_frag<<<dim3(50), 256, 0, stream>>>(Wq, wqF);
    ln_q_fused<<<dim3(512), 256, 0, stream>>>(x, gamma, beta, wqF, qF);
    gemm_kv<<<dim3(10, 5, 2), 256, 0, stream>>>(ctx, WkT, WvT, kbuf, vbuf);
    gemm_vw<<<dim3(5, 8, 8), 256, 0, stream>>>(WoutT, vbuf, vwT);
    repack_kf<<<dim3(160), 256, 0, stream>>>(kbuf, kF);
    repack_vwf<<<dim3(800), 256, 0, stream>>>(vwT, vwF);
    attn_out<<<dim3(1024), 256, 0, stream>>>(qF, kF, vwF, bout, x, out);
}

// Round 7
// 96.877 us; speedup vs baseline: 1.3852x; 1.0115x over previous
//
#include <hip/hip_runtime.h>

// ---------------- constants ----------------
#define HEADS 8
#define DH 40
constexpr int Bn   = 8;
constexpr int Cc   = 320;
constexpr int Nn   = 4096;        // tokens per batch (64*64)
constexpr int CTX  = 77;
constexpr float LN_EPS = 1e-5f;
constexpr float SCALE  = 0.15811388300841897f; // 40^-0.5

typedef short bf16x8 __attribute__((ext_vector_type(8)));
typedef float f32x4  __attribute__((ext_vector_type(4)));
typedef unsigned short us;

__device__ inline us f2bf(float f) {
    unsigned u = __float_as_uint(f);
    u += 0x7fffu + ((u >> 16) & 1u);
    return (us)(u >> 16);
}
__device__ inline float bf2f(us h) {
    return __uint_as_float(((unsigned)h) << 16);
}

// ---------------- weight prep: transposes (Wk,Wv,Wout) + Wq B-frag pack, one launch ----------------
__global__ __launch_bounds__(256) void wtrans_all(const float* __restrict__ Wq,
                                                  const float* __restrict__ Wk,
                                                  const float* __restrict__ Wv,
                                                  const float* __restrict__ Wout,
                                                  us* __restrict__ wqF,
                                                  us* __restrict__ WkT,
                                                  us* __restrict__ WvT,
                                                  us* __restrict__ WoutT) {
    int id = blockIdx.x;
    if (id >= 580) {
        // Wq -> MFMA B-fragment order: wqF[(ct*10+kc)][lane] = Wq[kc*32+g*8+e][ct*16+lr]
        int wid = (id - 580) * 4 + (threadIdx.x >> 6);  // 0..199
        int lane = threadIdx.x & 63, lr = lane & 15, g = lane >> 4;
        int ct = wid / 10, kc = wid % 10;
        int k0 = kc * 32 + g * 8, co = ct * 16 + lr;
        us tmp[8];
        #pragma unroll
        for (int e = 0; e < 8; ++e)
            tmp[e] = f2bf(Wq[(size_t)(k0 + e) * 320 + co]);
        ((uint4*)wqF)[(size_t)wid * 64 + lane] = *(uint4*)tmp;
        return;
    }
    const float* in; us* out; int K, t;
    if (id < 240)      { in = Wk;   out = WkT;   K = 768; t = id; }
    else if (id < 480) { in = Wv;   out = WvT;   K = 768; t = id - 240; }
    else               { in = Wout; out = WoutT; K = 320; t = id - 480; }
    int ktiles = K >> 5;
    int kb = (t % ktiles) * 32, ob = (t / ktiles) * 32;

    __shared__ float tile[32][33];
    int tx = threadIdx.x & 31, ty = threadIdx.x >> 5; // ty 0..7
    #pragma unroll
    for (int i = 0; i < 32; i += 8)
        tile[ty + i][tx] = in[(size_t)(kb + ty + i) * 320 + ob + tx];
    __syncthreads();
    #pragma unroll
    for (int i = 0; i < 32; i += 8)
        out[(size_t)(ob + ty + i) * K + kb + tx] = f2bf(tile[tx][ty + i]);
}

// ---------------- fused LayerNorm + Q projection -> qG (dense fragment order) ----------------
// x staged bf16 in LDS during stats pass (stats fp32-exact); normalize in place.
// qG frag id = gt*10 + f (gt = global 16-token tile, f = K/32); lane (g,lr) holds
// q[gt*16+lr][f*32 + g*8 .. +8].
__global__ __launch_bounds__(256, 3) void ln_q_fused(const float* __restrict__ x,
                                                     const float* __restrict__ gamma,
                                                     const float* __restrict__ beta,
                                                     const us* __restrict__ wqF,
                                                     us* __restrict__ qG) {
    __shared__ __align__(16) us xnt[64 * 328];
    __shared__ float red1[4][64], red2[4][64];
    __shared__ float mu_s[64], rs_s[64];

    int b  = blockIdx.x >> 6;
    int t0 = (blockIdx.x & 63) * 64;
    int tid = threadIdx.x;
    int tl = tid & 63, cg = tid >> 6;
    const float* xb = x + (size_t)b * Cc * Nn + t0 + tl;

    float s1 = 0.f, s2 = 0.f;
    #pragma unroll 8
    for (int i = 0; i < 80; ++i) {
        int c = cg * 80 + i;
        float v = xb[(size_t)c * Nn];
        s1 += v; s2 += v * v;
        xnt[tl * 328 + c] = f2bf(v);
    }
    red1[cg][tl] = s1; red2[cg][tl] = s2;
    __syncthreads();
    if (tid < 64) {
        float a1 = red1[0][tl] + red1[1][tl] + red1[2][tl] + red1[3][tl];
        float a2 = red2[0][tl] + red2[1][tl] + red2[2][tl] + red2[3][tl];
        float mu = a1 * (1.0f / Cc);
        float var = a2 * (1.0f / Cc) - mu * mu;
        mu_s[tl] = mu; rs_s[tl] = rsqrtf(var + LN_EPS);
    }
    __syncthreads();
    float mu = mu_s[tl], rs = rs_s[tl];
    #pragma unroll 4
    for (int i = 0; i < 40; ++i) {
        int c = cg * 80 + i * 2;
        unsigned u = *(unsigned*)&xnt[tl * 328 + c];
        float v0 = bf2f((us)(u & 0xffff));
        float v1 = bf2f((us)(u >> 16));
        unsigned lo = f2bf((v0 - mu) * rs * gamma[c]     + beta[c]);
        unsigned hi = f2bf((v1 - mu) * rs * gamma[c + 1] + beta[c + 1]);
        *(unsigned*)&xnt[tl * 328 + c] = lo | (hi << 16);
    }
    __syncthreads();

    int lane = tid & 63, w = tid >> 6;
    int lr = lane & 15, g = lane >> 4;
    f32x4 acc[4][5] = {};   // [token-tile][out-tile]
    const bf16x8* wq = (const bf16x8*)wqF;
    for (int kc = 0; kc < 10; ++kc) {
        bf16x8 bfr[5];
        #pragma unroll
        for (int nt = 0; nt < 5; ++nt)
            bfr[nt] = wq[(size_t)((w * 5 + nt) * 10 + kc) * 64 + lane];
        bf16x8 afr[4];
        #pragma unroll
        for (int mt = 0; mt < 4; ++mt)
            afr[mt] = *(const bf16x8*)&xnt[(mt * 16 + lr) * 328 + kc * 32 + g * 8];
        #pragma unroll
        for (int mt = 0; mt < 4; ++mt)
            #pragma unroll
            for (int nt = 0; nt < 5; ++nt)
                acc[mt][nt] = __builtin_amdgcn_mfma_f32_16x16x32_bf16(afr[mt], bfr[nt], acc[mt][nt], 0, 0, 0);
    }
    __syncthreads();   // xnt consumed; reuse as q-tile [64 tok][320 co]

    #pragma unroll
    for (int mt = 0; mt < 4; ++mt)
        #pragma unroll
        for (int nt = 0; nt < 5; ++nt)
            #pragma unroll
            for (int r = 0; r < 4; ++r)
                xnt[(mt * 16 + g * 4 + r) * 328 + w * 80 + nt * 16 + lr] = f2bf(acc[mt][nt][r]);
    __syncthreads();

    // emit 40 dense fragment blobs (4 tiles x 10 k-frags), 16B/lane coalesced
    size_t gtb = (size_t)b * 256 + (blockIdx.x & 63) * 4;
    #pragma unroll
    for (int it = 0; it < 10; ++it) {
        int f_lin = it * 4 + w;            // 0..39
        int tile = f_lin / 10, f = f_lin % 10;
        uint4 v = *(uint4*)&xnt[(tile * 16 + lr) * 328 + f * 32 + g * 8];
        ((uint4*)qG)[((gtb + tile) * 10 + f) * 64 + lane] = v;
    }
}

// ---------------- K/V projection: ctx fp32 [616][768] x W^T -> bf16 [616][320] ----------------
__global__ __launch_bounds__(256) void gemm_kv(const float* __restrict__ ctx,
                                               const us* __restrict__ WkT,
                                               const us* __restrict__ WvT,
                                               us* __restrict__ kbuf,
                                               us* __restrict__ vbuf) {
    const us* Bt = blockIdx.z ? WvT : WkT;
    us* Cm = blockIdx.z ? vbuf : kbuf;
    constexpr int K = 768, M = 616;
    __shared__ __align__(16) char Al[64 * 128];
    __shared__ __align__(16) char Bl[64 * 128];
    int m0 = blockIdx.x * 64;
    int n0 = blockIdx.y * 64;
    int tid = threadIdx.x;
    int lane = tid & 63, wave = tid >> 6;
    int wm = (wave >> 1) * 32, wn = (wave & 1) * 32;

    f32x4 acc[2][2] = {};

    for (int kc = 0; kc < K; kc += 64) {
        #pragma unroll
        for (int i = 0; i < 2; ++i) {
            int chunk = tid + 256 * i;
            int r = chunk >> 3, c8 = chunk & 7;
            int off = (r * 128 + c8 * 16) ^ ((r & 7) << 4);
            int gr = m0 + r;
            uint4 av = make_uint4(0, 0, 0, 0);
            if (gr < M) {
                float4 f0 = *(const float4*)(ctx + (size_t)gr * K + kc + c8 * 8);
                float4 f1 = *(const float4*)(ctx + (size_t)gr * K + kc + c8 * 8 + 4);
                av.x = f2bf(f0.x) | ((unsigned)f2bf(f0.y) << 16);
                av.y = f2bf(f0.z) | ((unsigned)f2bf(f0.w) << 16);
                av.z = f2bf(f1.x) | ((unsigned)f2bf(f1.y) << 16);
                av.w = f2bf(f1.z) | ((unsigned)f2bf(f1.w) << 16);
            }
            *(uint4*)(Al + off) = av;
            *(uint4*)(Bl + off) = *(const uint4*)(Bt + (size_t)(n0 + r) * K + kc + c8 * 8);
        }
        __syncthreads();

        #pragma unroll
        for (int kk = 0; kk < 64; kk += 32) {
            bf16x8 a[2], bfr[2];
            int lr = lane & 15;
            int lkb = (kk + (lane >> 4) * 8) * 2;
            #pragma unroll
            for (int mi = 0; mi < 2; ++mi) {
                int row = wm + mi * 16 + lr;
                a[mi] = *(const bf16x8*)(Al + ((row * 128 + lkb) ^ ((row & 7) << 4)));
            }
            #pragma unroll
            for (int ni = 0; ni < 2; ++ni) {
                int row = wn + ni * 16 + lr;
                bfr[ni] = *(const bf16x8*)(Bl + ((row * 128 + lkb) ^ ((row & 7) << 4)));
            }
            #pragma unroll
            for (int mi = 0; mi < 2; ++mi)
                #pragma unroll
                for (int ni = 0; ni < 2; ++ni)
                    acc[mi][ni] = __builtin_amdgcn_mfma_f32_16x16x32_bf16(a[mi], bfr[ni], acc[mi][ni], 0, 0, 0);
        }
        __syncthreads();
    }

    int lr = lane & 15, lq = lane >> 4;
    #pragma unroll
    for (int mi = 0; mi < 2; ++mi)
        #pragma unroll
        for (int ni = 0; ni < 2; ++ni)
            #pragma unroll
            for (int r = 0; r < 4; ++r) {
                int row = m0 + wm + mi * 16 + lq * 4 + r;
                int col = n0 + wn + ni * 16 + lr;
                if (row < M)
                    Cm[(size_t)row * 320 + col] = f2bf(acc[mi][ni][r]);
            }
}

// ---------------- VW precompute: vwT[b][c][h*80+j] = sum_d Wout[h*40+d][c] * V[b,j,h*40+d] ----------------
__global__ __launch_bounds__(256) void gemm_vw(const us* __restrict__ WoutT,
                                               const us* __restrict__ vbuf,
                                               us* __restrict__ vwT) {
    int b = blockIdx.z, h = blockIdx.y, cb = blockIdx.x * 64;
    int tid = threadIdx.x, lane = tid & 63, w = tid >> 6;
    int lr = lane & 15, g = lane >> 4;

    int crow = cb + w * 16 + lr;
    const us* ab = WoutT + (size_t)crow * 320 + h * DH;
    bf16x8 a0 = *(const bf16x8*)(ab + g * 8);
    bf16x8 a1 = {};
    if (g == 0) a1 = *(const bf16x8*)(ab + 32);

    f32x4 acc[5] = {};
    #pragma unroll
    for (int nt = 0; nt < 5; ++nt) {
        int j = nt * 16 + lr;
        bool jv = j < CTX;
        const us* kr = vbuf + (size_t)(b * CTX + (jv ? j : 0)) * 320 + h * DH;
        bf16x8 b0 = {}, b1 = {};
        if (jv) b0 = *(const bf16x8*)(kr + g * 8);
        if (jv && g == 0) b1 = *(const bf16x8*)(kr + 32);
        acc[nt] = __builtin_amdgcn_mfma_f32_16x16x32_bf16(a0, b0, acc[nt], 0, 0, 0);
        acc[nt] = __builtin_amdgcn_mfma_f32_16x16x32_bf16(a1, b1, acc[nt], 0, 0, 0);
    }

    #pragma unroll
    for (int nt = 0; nt < 5; ++nt)
        #pragma unroll
        for (int r = 0; r < 4; ++r) {
            int c = cb + w * 16 + g * 4 + r;
            float val = (nt == 4 && lr >= 13) ? 0.f : acc[nt][r];
            vwT[((size_t)(b * 320 + c)) * 640 + h * 80 + nt * 16 + lr] = f2bf(val);
        }
}

// ---------------- repack K + VW into MFMA-fragment order, one launch ----------------
__global__ __launch_bounds__(256) void repack_all(const us* __restrict__ kbuf,
                                                  const us* __restrict__ vwT,
                                                  us* __restrict__ kF,
                                                  us* __restrict__ vwF) {
    int id = blockIdx.x;
    int lane = threadIdx.x & 63, lr = lane & 15, g = lane >> 4;
    if (id < 160) {
        int wid = id * 4 + (threadIdx.x >> 6);       // 0..639
        int kc = wid & 1, nt = (wid >> 1) % 5, h = (wid / 10) & 7, b = wid / 80;
        int j = nt * 16 + lr, d0 = kc * 32 + g * 8;
        bf16x8 v = {};
        if (j < CTX && d0 < DH)
            v = *(const bf16x8*)(kbuf + ((size_t)(b * CTX + j)) * 320 + h * DH + d0);
        ((bf16x8*)kF)[(size_t)wid * 64 + lane] = v;
    } else {
        int wid = (id - 160) * 4 + (threadIdx.x >> 6);   // 0..3199
        int mi = wid % 5, ks = (wid / 5) % 20, w = (wid / 100) & 3, b = wid / 400;
        int co = w * 80 + mi * 16 + lr, k = ks * 32 + g * 8;
        bf16x8 v = *(const bf16x8*)(vwT + ((size_t)(b * 320 + co)) * 640 + k);
        ((bf16x8*)vwF)[(size_t)wid * 64 + lane] = v;
    }
}

// ---------------- fused attention + out-proj: 64 tokens/block, 2 k-half passes ----------------
// 512 blocks; b = bid&7 (XCD-local kF/vwF). Pass p: wave w handles head h=p*4+w:
// QK^T (dense qG gather + K frags) -> softmax -> P half [64][320] LDS -> PV half
// (K=320, vwF frags) accumulating o[5][4]. Epilogue: [b,c,n] store + bias + residual.
__global__ __launch_bounds__(256, 2) void attn_out(const us* __restrict__ qG,
                                                   const us* __restrict__ kF,
                                                   const us* __restrict__ vwF,
                                                   const float* __restrict__ bout,
                                                   const float* __restrict__ x,
                                                   float* __restrict__ out) {
    __shared__ __align__(16) char Pl[64 * 640];   // P bf16 [64][320], swizzled (40 KB)

    int bid = blockIdx.x;
    int b = bid & 7, ts = bid >> 3;
    int t0 = ts * 64;
    int tid = threadIdx.x, lane = tid & 63, w = tid >> 6;
    int lr = lane & 15, g = lane >> 4;

    const bf16x8* qfb = (const bf16x8*)qG;
    const bf16x8* kfb = (const bf16x8*)kF;

    f32x4 o[5][4] = {};

    #pragma unroll
    for (int p = 0; p < 2; ++p) {
        int h = p * 4 + w;
        // K frags for this head (reused across 4 token-tiles)
        size_t kfh = (size_t)((b * 8 + h) * 10) * 64;
        bf16x8 kb0[5], kb1[5];
        #pragma unroll
        for (int nt = 0; nt < 5; ++nt) {
            kb0[nt] = kfb[kfh + (nt * 2 + 0) * 64 + lane];
            kb1[nt] = kfb[kfh + (nt * 2 + 1) * 64 + lane];
        }
        // dense qG gather: k = 40h + 8g + e  ->  frag (5h+g)>>2, lane ((5h+g)&3)*16+lr
        int f0 = (5 * h + g) >> 2, l0 = ((5 * h + g) & 3) * 16 + lr;
        int f1 = (5 * h + 4) >> 2, l1 = ((5 * h + 4) & 3) * 16 + lr;

        #pragma unroll
        for (int mt = 0; mt < 4; ++mt) {
            const bf16x8* qt = qfb + (size_t)(b * 256 + ts * 4 + mt) * 640;
            bf16x8 a0 = qt[f0 * 64 + l0];
            bf16x8 a1 = {};
            if (g == 0) a1 = qt[f1 * 64 + l1];

            f32x4 S[5] = {};
            #pragma unroll
            for (int nt = 0; nt < 5; ++nt) {
                S[nt] = __builtin_amdgcn_mfma_f32_16x16x32_bf16(a0, kb0[nt], S[nt], 0, 0, 0);
                S[nt] = __builtin_amdgcn_mfma_f32_16x16x32_bf16(a1, kb1[nt], S[nt], 0, 0, 0);
            }

            float pv[5][4];
            #pragma unroll
            for (int nt = 0; nt < 5; ++nt)
                #pragma unroll
                for (int r = 0; r < 4; ++r)
                    pv[nt][r] = (nt == 4 && lr >= 13) ? 0.f : __expf(S[nt][r] * SCALE);
            #pragma unroll
            for (int r = 0; r < 4; ++r) {
                float su = pv[0][r] + pv[1][r] + pv[2][r] + pv[3][r] + pv[4][r];
                #pragma unroll
                for (int off = 1; off < 16; off <<= 1)
                    su += __shfl_xor(su, off);
                float inv = 1.0f / su;
                int row = mt * 16 + g * 4 + r;
                #pragma unroll
                for (int nt = 0; nt < 5; ++nt)
                    *(us*)(Pl + ((row * 640 + (w * 80 + nt * 16 + lr) * 2) ^ ((row & 7) << 4))) =
                        f2bf(pv[nt][r] * inv);
            }
        }
        __syncthreads();

        // PV half: o += VW[:, k-half] @ P^T (k_local 0..319)
        const bf16x8* vwb = (const bf16x8*)vwF + (size_t)(((b * 4 + w) * 20 + p * 10) * 5) * 64 + lane;
        __builtin_amdgcn_s_setprio(1);
        for (int ks = 0; ks < 10; ++ks) {
            bf16x8 av[5];
            #pragma unroll
            for (int mi = 0; mi < 5; ++mi)
                av[mi] = vwb[(ks * 5 + mi) * 64];
            bf16x8 pb[4];
            #pragma unroll
            for (int nt = 0; nt < 4; ++nt) {
                int row = nt * 16 + lr;
                pb[nt] = *(const bf16x8*)(Pl + ((row * 640 + ks * 64 + g * 16) ^ ((row & 7) << 4)));
            }
            #pragma unroll
            for (int mi = 0; mi < 5; ++mi)
                #pragma unroll
                for (int nt = 0; nt < 4; ++nt)
                    o[mi][nt] = __builtin_amdgcn_mfma_f32_16x16x32_bf16(av[mi], pb[nt], o[mi][nt], 0, 0, 0);
        }
        __builtin_amdgcn_s_setprio(0);
        __syncthreads();   // Pl reused by next pass
    }

    // ---- epilogue: coalesced store + bias + residual ----
    int cw = w * 80;
    #pragma unroll
    for (int mi = 0; mi < 5; ++mi)
        #pragma unroll
        for (int r = 0; r < 4; ++r) {
            int co = cw + mi * 16 + g * 4 + r;
            float bo = bout[co];
            #pragma unroll
            for (int nt = 0; nt < 4; ++nt) {
                size_t oi = ((size_t)(b * 320 + co)) * 4096 + t0 + nt * 16 + lr;
                out[oi] = o[mi][nt][r] + bo + x[oi];
            }
        }
}

// ---------------- launch ----------------
extern "C" void kernel_launch(void* const* d_in, const int* in_sizes, int n_in,
                              void* d_out, int out_size, void* d_ws, size_t ws_size,
                              hipStream_t stream) {
    const float* x     = (const float*)d_in[0];
    const float* ctx   = (const float*)d_in[1];
    const float* Wq    = (const float*)d_in[2];
    const float* Wk    = (const float*)d_in[3];
    const float* Wv    = (const float*)d_in[4];
    const float* Wout  = (const float*)d_in[5];
    const float* bout  = (const float*)d_in[6];
    const float* gamma = (const float*)d_in[7];
    const float* beta  = (const float*)d_in[8];
    float* out = (float*)d_out;
    char* ws = (char*)d_ws;

    // workspace layout (bytes)
    us* qG    = (us*)(ws);                 // 2048 tiles * 10 frags * 1 KB = 20971520
    us* kbuf  = (us*)(ws + 20971520);      // 394240
    us* vbuf  = (us*)(ws + 21365760);      // 394240
    us* vwT   = (us*)(ws + 21760000);      // 3276800
    us* vwF   = (us*)(ws + 25036800);      // 3276800
    us* kF    = (us*)(ws + 28313600);      // 655360
    us* wqF   = (us*)(ws + 28968960);      // 204800
    us* WkT   = (us*)(ws + 29173760);      // 491520
    us* WvT   = (us*)(ws + 29665280);      // 491520
    us* WoutT = (us*)(ws + 30156800);      // 204800

    wtrans_all<<<dim3(630), 256, 0, stream>>>(Wq, Wk, Wv, Wout, wqF, WkT, WvT, WoutT);
    gemm_kv<<<dim3(10, 5, 2), 256, 0, stream>>>(ctx, WkT, WvT, kbuf, vbuf);
    gemm_vw<<<dim3(5, 8, 8), 256, 0, stream>>>(WoutT, vbuf, vwT);
    repack_all<<<dim3(960), 256, 0, stream>>>(kbuf, vwT, kF, vwF);
    ln_q_fused<<<dim3(512), 256, 0, stream>>>(x, gamma, beta, wqF, qG);
    attn_out<<<dim3(512), 256, 0, stream>>>(qG, kF, vwF, bout, x, out);
}

// Round 8
// 91.656 us; speedup vs baseline: 1.4641x; 1.0570x over previous
//
#include <hip/hip_runtime.h>

// ---------------- constants ----------------
#define HEADS 8
#define DH 40
constexpr int Bn   = 8;
constexpr int Cc   = 320;
constexpr int Nn   = 4096;        // tokens per batch (64*64)
constexpr int CTX  = 77;
constexpr float LN_EPS = 1e-5f;
constexpr float SCALE  = 0.15811388300841897f; // 40^-0.5

typedef short bf16x8 __attribute__((ext_vector_type(8)));
typedef float f32x4  __attribute__((ext_vector_type(4)));
typedef unsigned short us;

__device__ inline us f2bf(float f) {
    unsigned u = __float_as_uint(f);
    u += 0x7fffu + ((u >> 16) & 1u);
    return (us)(u >> 16);
}
__device__ inline float bf2f(us h) {
    return __uint_as_float(((unsigned)h) << 16);
}

// ---------------- weight prep: transposes (Wk,Wv,Wout) + Wq B-frag pack, one launch ----------------
__global__ __launch_bounds__(256) void wtrans_all(const float* __restrict__ Wq,
                                                  const float* __restrict__ Wk,
                                                  const float* __restrict__ Wv,
                                                  const float* __restrict__ Wout,
                                                  us* __restrict__ wqF,
                                                  us* __restrict__ WkT,
                                                  us* __restrict__ WvT,
                                                  us* __restrict__ WoutT) {
    int id = blockIdx.x;
    if (id >= 580) {
        // Wq -> MFMA B-fragment order: wqF[(ct*10+kc)][lane] = Wq[kc*32+g*8+e][ct*16+lr]
        int wid = (id - 580) * 4 + (threadIdx.x >> 6);  // 0..199
        int lane = threadIdx.x & 63, lr = lane & 15, g = lane >> 4;
        int ct = wid / 10, kc = wid % 10;
        int k0 = kc * 32 + g * 8, co = ct * 16 + lr;
        us tmp[8];
        #pragma unroll
        for (int e = 0; e < 8; ++e)
            tmp[e] = f2bf(Wq[(size_t)(k0 + e) * 320 + co]);
        ((uint4*)wqF)[(size_t)wid * 64 + lane] = *(uint4*)tmp;
        return;
    }
    const float* in; us* out; int K, t;
    if (id < 240)      { in = Wk;   out = WkT;   K = 768; t = id; }
    else if (id < 480) { in = Wv;   out = WvT;   K = 768; t = id - 240; }
    else               { in = Wout; out = WoutT; K = 320; t = id - 480; }
    int ktiles = K >> 5;
    int kb = (t % ktiles) * 32, ob = (t / ktiles) * 32;

    __shared__ float tile[32][33];
    int tx = threadIdx.x & 31, ty = threadIdx.x >> 5; // ty 0..7
    #pragma unroll
    for (int i = 0; i < 32; i += 8)
        tile[ty + i][tx] = in[(size_t)(kb + ty + i) * 320 + ob + tx];
    __syncthreads();
    #pragma unroll
    for (int i = 0; i < 32; i += 8)
        out[(size_t)(ob + ty + i) * K + kb + tx] = f2bf(tile[tx][ty + i]);
}

// ---------------- fused LayerNorm + Q projection -> qG (dense fragment order) ----------------
__global__ __launch_bounds__(256, 3) void ln_q_fused(const float* __restrict__ x,
                                                     const float* __restrict__ gamma,
                                                     const float* __restrict__ beta,
                                                     const us* __restrict__ wqF,
                                                     us* __restrict__ qG) {
    __shared__ __align__(16) us xnt[64 * 328];
    __shared__ float red1[4][64], red2[4][64];
    __shared__ float mu_s[64], rs_s[64];

    int b  = blockIdx.x >> 6;
    int t0 = (blockIdx.x & 63) * 64;
    int tid = threadIdx.x;
    int tl = tid & 63, cg = tid >> 6;
    const float* xb = x + (size_t)b * Cc * Nn + t0 + tl;

    float s1 = 0.f, s2 = 0.f;
    #pragma unroll 8
    for (int i = 0; i < 80; ++i) {
        int c = cg * 80 + i;
        float v = xb[(size_t)c * Nn];
        s1 += v; s2 += v * v;
        xnt[tl * 328 + c] = f2bf(v);
    }
    red1[cg][tl] = s1; red2[cg][tl] = s2;
    __syncthreads();
    if (tid < 64) {
        float a1 = red1[0][tl] + red1[1][tl] + red1[2][tl] + red1[3][tl];
        float a2 = red2[0][tl] + red2[1][tl] + red2[2][tl] + red2[3][tl];
        float mu = a1 * (1.0f / Cc);
        float var = a2 * (1.0f / Cc) - mu * mu;
        mu_s[tl] = mu; rs_s[tl] = rsqrtf(var + LN_EPS);
    }
    __syncthreads();
    float mu = mu_s[tl], rs = rs_s[tl];
    #pragma unroll 4
    for (int i = 0; i < 40; ++i) {
        int c = cg * 80 + i * 2;
        unsigned u = *(unsigned*)&xnt[tl * 328 + c];
        float v0 = bf2f((us)(u & 0xffff));
        float v1 = bf2f((us)(u >> 16));
        unsigned lo = f2bf((v0 - mu) * rs * gamma[c]     + beta[c]);
        unsigned hi = f2bf((v1 - mu) * rs * gamma[c + 1] + beta[c + 1]);
        *(unsigned*)&xnt[tl * 328 + c] = lo | (hi << 16);
    }
    __syncthreads();

    int lane = tid & 63, w = tid >> 6;
    int lr = lane & 15, g = lane >> 4;
    f32x4 acc[4][5] = {};   // [token-tile][out-tile]
    const bf16x8* wq = (const bf16x8*)wqF;
    for (int kc = 0; kc < 10; ++kc) {
        bf16x8 bfr[5];
        #pragma unroll
        for (int nt = 0; nt < 5; ++nt)
            bfr[nt] = wq[(size_t)((w * 5 + nt) * 10 + kc) * 64 + lane];
        bf16x8 afr[4];
        #pragma unroll
        for (int mt = 0; mt < 4; ++mt)
            afr[mt] = *(const bf16x8*)&xnt[(mt * 16 + lr) * 328 + kc * 32 + g * 8];
        #pragma unroll
        for (int mt = 0; mt < 4; ++mt)
            #pragma unroll
            for (int nt = 0; nt < 5; ++nt)
                acc[mt][nt] = __builtin_amdgcn_mfma_f32_16x16x32_bf16(afr[mt], bfr[nt], acc[mt][nt], 0, 0, 0);
    }
    __syncthreads();   // xnt consumed; reuse as q-tile [64 tok][320 co]

    #pragma unroll
    for (int mt = 0; mt < 4; ++mt)
        #pragma unroll
        for (int nt = 0; nt < 5; ++nt)
            #pragma unroll
            for (int r = 0; r < 4; ++r)
                xnt[(mt * 16 + g * 4 + r) * 328 + w * 80 + nt * 16 + lr] = f2bf(acc[mt][nt][r]);
    __syncthreads();

    // emit 40 dense fragment blobs (4 tiles x 10 k-frags), 16B/lane coalesced
    size_t gtb = (size_t)b * 256 + (blockIdx.x & 63) * 4;
    #pragma unroll
    for (int it = 0; it < 10; ++it) {
        int f_lin = it * 4 + w;            // 0..39
        int tile = f_lin / 10, f = f_lin % 10;
        uint4 v = *(uint4*)&xnt[(tile * 16 + lr) * 328 + f * 32 + g * 8];
        ((uint4*)qG)[((gtb + tile) * 10 + f) * 64 + lane] = v;
    }
}

// ---------------- K/V projection: ctx fp32 [616][768] x W^T -> bf16 [616][320] ----------------
__global__ __launch_bounds__(256) void gemm_kv(const float* __restrict__ ctx,
                                               const us* __restrict__ WkT,
                                               const us* __restrict__ WvT,
                                               us* __restrict__ kbuf,
                                               us* __restrict__ vbuf) {
    const us* Bt = blockIdx.z ? WvT : WkT;
    us* Cm = blockIdx.z ? vbuf : kbuf;
    constexpr int K = 768, M = 616;
    __shared__ __align__(16) char Al[64 * 128];
    __shared__ __align__(16) char Bl[64 * 128];
    int m0 = blockIdx.x * 64;
    int n0 = blockIdx.y * 64;
    int tid = threadIdx.x;
    int lane = tid & 63, wave = tid >> 6;
    int wm = (wave >> 1) * 32, wn = (wave & 1) * 32;

    f32x4 acc[2][2] = {};

    for (int kc = 0; kc < K; kc += 64) {
        #pragma unroll
        for (int i = 0; i < 2; ++i) {
            int chunk = tid + 256 * i;
            int r = chunk >> 3, c8 = chunk & 7;
            int off = (r * 128 + c8 * 16) ^ ((r & 7) << 4);
            int gr = m0 + r;
            uint4 av = make_uint4(0, 0, 0, 0);
            if (gr < M) {
                float4 f0 = *(const float4*)(ctx + (size_t)gr * K + kc + c8 * 8);
                float4 f1 = *(const float4*)(ctx + (size_t)gr * K + kc + c8 * 8 + 4);
                av.x = f2bf(f0.x) | ((unsigned)f2bf(f0.y) << 16);
                av.y = f2bf(f0.z) | ((unsigned)f2bf(f0.w) << 16);
                av.z = f2bf(f1.x) | ((unsigned)f2bf(f1.y) << 16);
                av.w = f2bf(f1.z) | ((unsigned)f2bf(f1.w) << 16);
            }
            *(uint4*)(Al + off) = av;
            *(uint4*)(Bl + off) = *(const uint4*)(Bt + (size_t)(n0 + r) * K + kc + c8 * 8);
        }
        __syncthreads();

        #pragma unroll
        for (int kk = 0; kk < 64; kk += 32) {
            bf16x8 a[2], bfr[2];
            int lr = lane & 15;
            int lkb = (kk + (lane >> 4) * 8) * 2;
            #pragma unroll
            for (int mi = 0; mi < 2; ++mi) {
                int row = wm + mi * 16 + lr;
                a[mi] = *(const bf16x8*)(Al + ((row * 128 + lkb) ^ ((row & 7) << 4)));
            }
            #pragma unroll
            for (int ni = 0; ni < 2; ++ni) {
                int row = wn + ni * 16 + lr;
                bfr[ni] = *(const bf16x8*)(Bl + ((row * 128 + lkb) ^ ((row & 7) << 4)));
            }
            #pragma unroll
            for (int mi = 0; mi < 2; ++mi)
                #pragma unroll
                for (int ni = 0; ni < 2; ++ni)
                    acc[mi][ni] = __builtin_amdgcn_mfma_f32_16x16x32_bf16(a[mi], bfr[ni], acc[mi][ni], 0, 0, 0);
        }
        __syncthreads();
    }

    int lr = lane & 15, lq = lane >> 4;
    #pragma unroll
    for (int mi = 0; mi < 2; ++mi)
        #pragma unroll
        for (int ni = 0; ni < 2; ++ni)
            #pragma unroll
            for (int r = 0; r < 4; ++r) {
                int row = m0 + wm + mi * 16 + lq * 4 + r;
                int col = n0 + wn + ni * 16 + lr;
                if (row < M)
                    Cm[(size_t)row * 320 + col] = f2bf(acc[mi][ni][r]);
            }
}

// ---------------- VW precompute: vwT[b][c][h*80+j] = sum_d Wout[h*40+d][c] * V[b,j,h*40+d] ----------------
__global__ __launch_bounds__(256) void gemm_vw(const us* __restrict__ WoutT,
                                               const us* __restrict__ vbuf,
                                               us* __restrict__ vwT) {
    int b = blockIdx.z, h = blockIdx.y, cb = blockIdx.x * 64;
    int tid = threadIdx.x, lane = tid & 63, w = tid >> 6;
    int lr = lane & 15, g = lane >> 4;

    int crow = cb + w * 16 + lr;
    const us* ab = WoutT + (size_t)crow * 320 + h * DH;
    bf16x8 a0 = *(const bf16x8*)(ab + g * 8);
    bf16x8 a1 = {};
    if (g == 0) a1 = *(const bf16x8*)(ab + 32);

    f32x4 acc[5] = {};
    #pragma unroll
    for (int nt = 0; nt < 5; ++nt) {
        int j = nt * 16 + lr;
        bool jv = j < CTX;
        const us* kr = vbuf + (size_t)(b * CTX + (jv ? j : 0)) * 320 + h * DH;
        bf16x8 b0 = {}, b1 = {};
        if (jv) b0 = *(const bf16x8*)(kr + g * 8);
        if (jv && g == 0) b1 = *(const bf16x8*)(kr + 32);
        acc[nt] = __builtin_amdgcn_mfma_f32_16x16x32_bf16(a0, b0, acc[nt], 0, 0, 0);
        acc[nt] = __builtin_amdgcn_mfma_f32_16x16x32_bf16(a1, b1, acc[nt], 0, 0, 0);
    }

    #pragma unroll
    for (int nt = 0; nt < 5; ++nt)
        #pragma unroll
        for (int r = 0; r < 4; ++r) {
            int c = cb + w * 16 + g * 4 + r;
            float val = (nt == 4 && lr >= 13) ? 0.f : acc[nt][r];
            vwT[((size_t)(b * 320 + c)) * 640 + h * 80 + nt * 16 + lr] = f2bf(val);
        }
}

// ---------------- repack K + VW into MFMA-fragment order, one launch ----------------
__global__ __launch_bounds__(256) void repack_all(const us* __restrict__ kbuf,
                                                  const us* __restrict__ vwT,
                                                  us* __restrict__ kF,
                                                  us* __restrict__ vwF) {
    int id = blockIdx.x;
    int lane = threadIdx.x & 63, lr = lane & 15, g = lane >> 4;
    if (id < 160) {
        int wid = id * 4 + (threadIdx.x >> 6);       // 0..639
        int kc = wid & 1, nt = (wid >> 1) % 5, h = (wid / 10) & 7, b = wid / 80;
        int j = nt * 16 + lr, d0 = kc * 32 + g * 8;
        bf16x8 v = {};
        if (j < CTX && d0 < DH)
            v = *(const bf16x8*)(kbuf + ((size_t)(b * CTX + j)) * 320 + h * DH + d0);
        ((bf16x8*)kF)[(size_t)wid * 64 + lane] = v;
    } else {
        int wid = (id - 160) * 4 + (threadIdx.x >> 6);   // 0..3199
        int mi = wid % 5, ks = (wid / 5) % 20, w = (wid / 100) & 3, b = wid / 400;
        int co = w * 80 + mi * 16 + lr, k = ks * 32 + g * 8;
        bf16x8 v = *(const bf16x8*)(vwT + ((size_t)(b * 320 + co)) * 640 + k);
        ((bf16x8*)vwF)[(size_t)wid * 64 + lane] = v;
    }
}

// ---------------- fused attention + out-proj: 512 threads, 64 tokens/block, single pass ----------------
// 8 waves: QK^T+softmax with wave=head (P -> [64][640] LDS, 80 KB), one barrier,
// PV with wave=(co-slice 80, token-half 32), K=640 over vwF frags. Epilogue coalesced.
__global__ __launch_bounds__(512, 4) void attn_out(const us* __restrict__ qG,
                                                   const us* __restrict__ kF,
                                                   const us* __restrict__ vwF,
                                                   const float* __restrict__ bout,
                                                   const float* __restrict__ x,
                                                   float* __restrict__ out) {
    __shared__ __align__(16) char Pl[64 * 1280];   // P bf16 [64][640], swizzled (80 KB)

    int bid = blockIdx.x;
    int b = bid & 7, ts = bid >> 3;       // XCD-local batch
    int t0 = ts * 64;
    int tid = threadIdx.x, lane = tid & 63, w = tid >> 6;   // w 0..7
    int lr = lane & 15, g = lane >> 4;

    const bf16x8* qfb = (const bf16x8*)qG;
    const bf16x8* kfb = (const bf16x8*)kF;

    // ---- QK^T + softmax: wave w = head w ----
    {
        int h = w;
        size_t kfh = (size_t)((b * 8 + h) * 10) * 64;
        bf16x8 kb0[5], kb1[5];
        #pragma unroll
        for (int nt = 0; nt < 5; ++nt) {
            kb0[nt] = kfb[kfh + (nt * 2 + 0) * 64 + lane];
            kb1[nt] = kfb[kfh + (nt * 2 + 1) * 64 + lane];
        }
        // dense qG gather: k = 40h + 8g + e  ->  frag (5h+g)>>2, lane ((5h+g)&3)*16+lr
        int f0 = (5 * h + g) >> 2, l0 = ((5 * h + g) & 3) * 16 + lr;
        int f1 = (5 * h + 4) >> 2, l1 = ((5 * h + 4) & 3) * 16 + lr;

        #pragma unroll
        for (int mt = 0; mt < 4; ++mt) {
            const bf16x8* qt = qfb + (size_t)(b * 256 + ts * 4 + mt) * 640;
            bf16x8 a0 = qt[f0 * 64 + l0];
            bf16x8 a1 = {};
            if (g == 0) a1 = qt[f1 * 64 + l1];

            f32x4 S[5] = {};
            #pragma unroll
            for (int nt = 0; nt < 5; ++nt) {
                S[nt] = __builtin_amdgcn_mfma_f32_16x16x32_bf16(a0, kb0[nt], S[nt], 0, 0, 0);
                S[nt] = __builtin_amdgcn_mfma_f32_16x16x32_bf16(a1, kb1[nt], S[nt], 0, 0, 0);
            }

            float pv[5][4];
            #pragma unroll
            for (int nt = 0; nt < 5; ++nt)
                #pragma unroll
                for (int r = 0; r < 4; ++r)
                    pv[nt][r] = (nt == 4 && lr >= 13) ? 0.f : __expf(S[nt][r] * SCALE);
            #pragma unroll
            for (int r = 0; r < 4; ++r) {
                float su = pv[0][r] + pv[1][r] + pv[2][r] + pv[3][r] + pv[4][r];
                #pragma unroll
                for (int off = 1; off < 16; off <<= 1)
                    su += __shfl_xor(su, off);
                float inv = 1.0f / su;
                int row = mt * 16 + g * 4 + r;
                #pragma unroll
                for (int nt = 0; nt < 5; ++nt)
                    *(us*)(Pl + ((row * 1280 + (h * 80 + nt * 16 + lr) * 2) ^ ((row & 7) << 4))) =
                        f2bf(pv[nt][r] * inv);
            }
        }
    }
    __syncthreads();

    // ---- PV: out^T = VW^T @ P^T, K=640; wave -> (wc = co-slice, wt = token-half) ----
    int wc = w >> 1, wt = w & 1;
    f32x4 o[5][2] = {};
    const bf16x8* vwb = (const bf16x8*)vwF + (size_t)((b * 4 + wc) * 100) * 64 + lane;
    __builtin_amdgcn_s_setprio(1);
    for (int ks = 0; ks < 20; ++ks) {
        bf16x8 av[5];
        #pragma unroll
        for (int mi = 0; mi < 5; ++mi)
            av[mi] = vwb[(ks * 5 + mi) * 64];
        bf16x8 pb[2];
        #pragma unroll
        for (int nt = 0; nt < 2; ++nt) {
            int row = wt * 32 + nt * 16 + lr;
            pb[nt] = *(const bf16x8*)(Pl + ((row * 1280 + ks * 64 + g * 16) ^ ((row & 7) << 4)));
        }
        #pragma unroll
        for (int mi = 0; mi < 5; ++mi)
            #pragma unroll
            for (int nt = 0; nt < 2; ++nt)
                o[mi][nt] = __builtin_amdgcn_mfma_f32_16x16x32_bf16(av[mi], pb[nt], o[mi][nt], 0, 0, 0);
    }
    __builtin_amdgcn_s_setprio(0);

    // ---- epilogue: coalesced store + bias + residual ----
    int cw = wc * 80;
    #pragma unroll
    for (int mi = 0; mi < 5; ++mi)
        #pragma unroll
        for (int r = 0; r < 4; ++r) {
            int co = cw + mi * 16 + g * 4 + r;
            float bo = bout[co];
            #pragma unroll
            for (int nt = 0; nt < 2; ++nt) {
                size_t oi = ((size_t)(b * 320 + co)) * 4096 + t0 + wt * 32 + nt * 16 + lr;
                out[oi] = o[mi][nt][r] + bo + x[oi];
            }
        }
}

// ---------------- launch ----------------
extern "C" void kernel_launch(void* const* d_in, const int* in_sizes, int n_in,
                              void* d_out, int out_size, void* d_ws, size_t ws_size,
                              hipStream_t stream) {
    const float* x     = (const float*)d_in[0];
    const float* ctx   = (const float*)d_in[1];
    const float* Wq    = (const float*)d_in[2];
    const float* Wk    = (const float*)d_in[3];
    const float* Wv    = (const float*)d_in[4];
    const float* Wout  = (const float*)d_in[5];
    const float* bout  = (const float*)d_in[6];
    const float* gamma = (const float*)d_in[7];
    const float* beta  = (const float*)d_in[8];
    float* out = (float*)d_out;
    char* ws = (char*)d_ws;

    // workspace layout (bytes)
    us* qG    = (us*)(ws);                 // 2048 tiles * 10 frags * 1 KB = 20971520
    us* kbuf  = (us*)(ws + 20971520);      // 394240
    us* vbuf  = (us*)(ws + 21365760);      // 394240
    us* vwT   = (us*)(ws + 21760000);      // 3276800
    us* vwF   = (us*)(ws + 25036800);      // 3276800
    us* kF    = (us*)(ws + 28313600);      // 655360
    us* wqF   = (us*)(ws + 28968960);      // 204800
    us* WkT   = (us*)(ws + 29173760);      // 491520
    us* WvT   = (us*)(ws + 29665280);      // 491520
    us* WoutT = (us*)(ws + 30156800);      // 204800

    wtrans_all<<<dim3(630), 256, 0, stream>>>(Wq, Wk, Wv, Wout, wqF, WkT, WvT, WoutT);
    gemm_kv<<<dim3(10, 5, 2), 256, 0, stream>>>(ctx, WkT, WvT, kbuf, vbuf);
    gemm_vw<<<dim3(5, 8, 8), 256, 0, stream>>>(WoutT, vbuf, vwT);
    repack_all<<<dim3(960), 256, 0, stream>>>(kbuf, vwT, kF, vwF);
    ln_q_fused<<<dim3(512), 256, 0, stream>>>(x, gamma, beta, wqF, qG);
    attn_out<<<dim3(512), 512, 0, stream>>>(qG, kF, vwF, bout, x, out);
}